// Round 2
// baseline (960.209 us; speedup 1.0000x reference)
//
#include <hip/hip_runtime.h>

#define N_NODES 50000
#define N_EDGES 800000

// ---------------- CSR build ----------------

__global__ void hist_kernel(const int* __restrict__ dst, int* __restrict__ deg, int e) {
    int i = blockIdx.x * blockDim.x + threadIdx.x;
    if (i < e) atomicAdd(&deg[dst[i]], 1);
}

__global__ void dinv_kernel(const int* __restrict__ deg, float* __restrict__ dinv, int n) {
    int i = blockIdx.x * blockDim.x + threadIdx.x;
    if (i < n) dinv[i] = rsqrtf((float)deg[i] + 1.0f);
}

// single-block exclusive scan over n counts -> row_start[0..n]
// wave-shuffle based: 4 barriers per 1024 elements (old version: ~20)
__global__ __launch_bounds__(1024) void scan_kernel(const int* __restrict__ counts,
                                                    int* __restrict__ row_start, int n) {
    __shared__ int wsum[16];
    __shared__ int carry_s;
    int tid = threadIdx.x, wid = tid >> 6, lane = tid & 63;
    if (tid == 0) carry_s = 0;
    __syncthreads();
    for (int base = 0; base < n; base += 1024) {
        int i = base + tid;
        int v = (i < n) ? counts[i] : 0;
        int s = v;  // inclusive wave scan
        #pragma unroll
        for (int off = 1; off < 64; off <<= 1) {
            int t = __shfl_up(s, off, 64);
            if (lane >= off) s += t;
        }
        if (lane == 63) wsum[wid] = s;
        __syncthreads();
        if (wid == 0) {
            int ws = (lane < 16) ? wsum[lane] : 0;
            #pragma unroll
            for (int off = 1; off < 16; off <<= 1) {
                int t = __shfl_up(ws, off, 64);
                if (lane >= off) ws += t;
            }
            if (lane < 16) wsum[lane] = ws;   // inclusive scan of wave totals
        }
        __syncthreads();
        int carry = carry_s;
        if (i < n) row_start[i] = carry + ((wid == 0) ? 0 : wsum[wid - 1]) + s - v;
        int total = wsum[15];
        __syncthreads();
        if (tid == 0) carry_s = carry + total;
        __syncthreads();
    }
    if (tid == 0) row_start[n] = carry_s;
}

__global__ void scatter_kernel(const int* __restrict__ src, const int* __restrict__ dst,
                               const float* __restrict__ dinv,
                               const int* __restrict__ row_start, int* __restrict__ cursor,
                               int* __restrict__ csr_src, float* __restrict__ csr_w, int e) {
    int i = blockIdx.x * blockDim.x + threadIdx.x;
    if (i < e) {
        int d = dst[i], s = src[i];
        int p = atomicAdd(&cursor[d], 1);
        int idx = row_start[d] + p;
        csr_src[idx] = s;
        csr_w[idx] = dinv[s] * dinv[d];
    }
}

// ---------------- fp32 tiled GEMM: C[M,N] = A[M,K] @ B[K,N] ----------------
// BM=BN=128, BK=16, 256 threads, 8x8 microtile per thread.
// As stored k-major (transposed) so inner-loop A reads are float4.

__global__ __launch_bounds__(256, 2) void gemm_kernel(const float* __restrict__ A,
                                                      const float* __restrict__ B,
                                                      float* __restrict__ C,
                                                      int M, int N, int K) {
    constexpr int BM = 128, BN = 128, BK = 16;
    __shared__ float As[BK][BM + 4];
    __shared__ float Bs[BK][BN + 4];
    int tid = threadIdx.x;
    int tx = tid & 15, ty = tid >> 4;          // 16x16 thread grid
    int bm = blockIdx.x * BM;
    int bn = blockIdx.y * BN;
    float acc[8][8] = {};

    // A staging: 128 rows x 16 cols, 8 floats/thread
    int ar = tid >> 1;                 // 0..127
    int ac = (tid & 1) * 8;            // 0 or 8
    const bool arow_ok = (bm + ar) < M;
    const float* Aptr = A + (size_t)(bm + ar) * K + ac;
    // B staging: 16 rows x 128 cols, 8 floats/thread
    int br = tid >> 4;                 // 0..15
    int bc = (tid & 15) * 8;           // 0..120
    const float* Bptr = B + (size_t)br * N + bn + bc;

    for (int k0 = 0; k0 < K; k0 += BK) {
        float4 a0 = {0.f, 0.f, 0.f, 0.f}, a1 = {0.f, 0.f, 0.f, 0.f};
        if (arow_ok) {
            a0 = *(const float4*)(Aptr + k0);
            a1 = *(const float4*)(Aptr + k0 + 4);
        }
        float4 b0 = *(const float4*)(Bptr + (size_t)k0 * N);
        float4 b1 = *(const float4*)(Bptr + (size_t)k0 * N + 4);
        __syncthreads();
        As[ac + 0][ar] = a0.x; As[ac + 1][ar] = a0.y;
        As[ac + 2][ar] = a0.z; As[ac + 3][ar] = a0.w;
        As[ac + 4][ar] = a1.x; As[ac + 5][ar] = a1.y;
        As[ac + 6][ar] = a1.z; As[ac + 7][ar] = a1.w;
        *(float4*)&Bs[br][bc] = b0;
        *(float4*)&Bs[br][bc + 4] = b1;
        __syncthreads();
        #pragma unroll
        for (int k = 0; k < BK; ++k) {
            float4 x0 = *(const float4*)&As[k][ty * 8];
            float4 x1 = *(const float4*)&As[k][ty * 8 + 4];
            float4 y0 = *(const float4*)&Bs[k][tx * 8];
            float4 y1 = *(const float4*)&Bs[k][tx * 8 + 4];
            float a[8] = {x0.x, x0.y, x0.z, x0.w, x1.x, x1.y, x1.z, x1.w};
            float b[8] = {y0.x, y0.y, y0.z, y0.w, y1.x, y1.y, y1.z, y1.w};
            #pragma unroll
            for (int i = 0; i < 8; ++i)
                #pragma unroll
                for (int j = 0; j < 8; ++j)
                    acc[i][j] = fmaf(a[i], b[j], acc[i][j]);
        }
    }
    #pragma unroll
    for (int i = 0; i < 8; ++i) {
        int row = bm + ty * 8 + i;
        if (row < M) {
            float4 o0 = make_float4(acc[i][0], acc[i][1], acc[i][2], acc[i][3]);
            float4 o1 = make_float4(acc[i][4], acc[i][5], acc[i][6], acc[i][7]);
            *(float4*)&C[(size_t)row * N + bn + tx * 8] = o0;
            *(float4*)&C[(size_t)row * N + bn + tx * 8 + 4] = o1;
        }
    }
}

// ---------------- aggregation: out = relu(A_hat @ hlin + bias) ----------------
// one wave per node; VEC floats per lane (VEC=4 -> 256 cols, VEC=2 -> 128 cols)
// edge metadata loaded cooperatively (64 edges/load) and shfl-broadcast.

template <int VEC>
__global__ __launch_bounds__(256) void aggregate_kernel(
    const float* __restrict__ hlin, const int* __restrict__ row_start,
    const int* __restrict__ csr_src, const float* __restrict__ csr_w,
    const float* __restrict__ dinv, const float* __restrict__ bias,
    float* __restrict__ out, int n) {
    constexpr int COLS = 64 * VEC;
    int node = blockIdx.x * 4 + (threadIdx.x >> 6);
    int lane = threadIdx.x & 63;
    if (node >= n) return;
    int c0 = lane * VEC;

    float acc[VEC];
    float dn = dinv[node];
    float ns = dn * dn;
    {
        const float* r = hlin + (size_t)node * COLS + c0;
        if constexpr (VEC == 4) {
            float4 v = *(const float4*)r;
            acc[0] = v.x * ns; acc[1] = v.y * ns; acc[2] = v.z * ns; acc[3] = v.w * ns;
        } else {
            float2 v = *(const float2*)r;
            acc[0] = v.x * ns; acc[1] = v.y * ns;
        }
    }
    int beg = row_start[node], end = row_start[node + 1];
    int deg = end - beg;
    for (int base = 0; base < deg; base += 64) {
        int cnt = min(64, deg - base);
        int es = 0; float ew = 0.f;
        if (lane < cnt) {
            es = csr_src[beg + base + lane];
            ew = csr_w[beg + base + lane];
        }
        int i = 0;
        for (; i + 1 < cnt; i += 2) {
            int s0 = __shfl(es, i, 64);     float w0 = __shfl(ew, i, 64);
            int s1 = __shfl(es, i + 1, 64); float w1 = __shfl(ew, i + 1, 64);
            const float* r0 = hlin + (size_t)s0 * COLS + c0;
            const float* r1 = hlin + (size_t)s1 * COLS + c0;
            if constexpr (VEC == 4) {
                float4 v0 = *(const float4*)r0;
                float4 v1 = *(const float4*)r1;
                acc[0] = fmaf(w0, v0.x, acc[0]); acc[1] = fmaf(w0, v0.y, acc[1]);
                acc[2] = fmaf(w0, v0.z, acc[2]); acc[3] = fmaf(w0, v0.w, acc[3]);
                acc[0] = fmaf(w1, v1.x, acc[0]); acc[1] = fmaf(w1, v1.y, acc[1]);
                acc[2] = fmaf(w1, v1.z, acc[2]); acc[3] = fmaf(w1, v1.w, acc[3]);
            } else {
                float2 v0 = *(const float2*)r0;
                float2 v1 = *(const float2*)r1;
                acc[0] = fmaf(w0, v0.x, acc[0]); acc[1] = fmaf(w0, v0.y, acc[1]);
                acc[0] = fmaf(w1, v1.x, acc[0]); acc[1] = fmaf(w1, v1.y, acc[1]);
            }
        }
        if (i < cnt) {
            int s = __shfl(es, i, 64); float w = __shfl(ew, i, 64);
            const float* r = hlin + (size_t)s * COLS + c0;
            if constexpr (VEC == 4) {
                float4 v = *(const float4*)r;
                acc[0] = fmaf(w, v.x, acc[0]); acc[1] = fmaf(w, v.y, acc[1]);
                acc[2] = fmaf(w, v.z, acc[2]); acc[3] = fmaf(w, v.w, acc[3]);
            } else {
                float2 v = *(const float2*)r;
                acc[0] = fmaf(w, v.x, acc[0]); acc[1] = fmaf(w, v.y, acc[1]);
            }
        }
    }
    #pragma unroll
    for (int v = 0; v < VEC; ++v) {
        float val = acc[v] + bias[c0 + v];
        out[(size_t)node * COLS + c0 + v] = fmaxf(val, 0.0f);
    }
}

// ---------------- fused 3-head output: out[n][9] = h3 @ [We|Wh|Wg] + [be|bh|bg] ----------------

__global__ __launch_bounds__(256) void head_kernel(const float* __restrict__ h3,
                                                   const float* __restrict__ We, const float* __restrict__ be,
                                                   const float* __restrict__ Wh, const float* __restrict__ bh,
                                                   const float* __restrict__ Wg, const float* __restrict__ bg,
                                                   float* __restrict__ out, int n) {
    __shared__ float Ws[128][9];
    __shared__ float bs[9];
    int tid = threadIdx.x;
    for (int i = tid; i < 128 * 3; i += 256) {
        int r = i / 3, c = i % 3;
        Ws[r][c]     = We[i];
        Ws[r][c + 3] = Wh[i];
        Ws[r][c + 6] = Wg[i];
    }
    if (tid < 3) { bs[tid] = be[tid]; bs[tid + 3] = bh[tid]; bs[tid + 6] = bg[tid]; }
    __syncthreads();
    int node = blockIdx.x * 4 + (tid >> 6);
    int lane = tid & 63;
    if (node >= n) return;
    float2 v = *(const float2*)(h3 + (size_t)node * 128 + lane * 2);
    #pragma unroll
    for (int c = 0; c < 9; ++c) {
        float p = v.x * Ws[lane * 2][c] + v.y * Ws[lane * 2 + 1][c];
        #pragma unroll
        for (int m = 1; m < 64; m <<= 1) p += __shfl_xor(p, m, 64);
        if (lane == 0) out[(size_t)node * 9 + c] = p + bs[c];
    }
}

// ---------------- launch ----------------

extern "C" void kernel_launch(void* const* d_in, const int* in_sizes, int n_in,
                              void* d_out, int out_size, void* d_ws, size_t ws_size,
                              hipStream_t stream) {
    const float* x  = (const float*)d_in[0];
    const int*   ei = (const int*)d_in[1];
    const float* W1 = (const float*)d_in[2];
    const float* b1 = (const float*)d_in[3];
    const float* W2 = (const float*)d_in[4];
    const float* b2 = (const float*)d_in[5];
    const float* W3 = (const float*)d_in[6];
    const float* b3 = (const float*)d_in[7];
    const float* We = (const float*)d_in[8];
    const float* be = (const float*)d_in[9];
    const float* Wh = (const float*)d_in[10];
    const float* bh = (const float*)d_in[11];
    const float* Wg = (const float*)d_in[12];
    const float* bg = (const float*)d_in[13];
    float* out = (float*)d_out;

    const int* src = ei;            // edge_index[0]
    const int* dst = ei + N_EDGES;  // edge_index[1]

    char* ws = (char*)d_ws;
    size_t off = 0;
    auto alloc = [&](size_t bytes) {
        void* p = ws + off;
        off = (off + bytes + 255) & ~(size_t)255;
        return p;
    };
    int*   deg       = (int*)alloc(N_NODES * 4);
    float* dinv      = (float*)alloc(N_NODES * 4);
    int*   row_start = (int*)alloc((N_NODES + 1) * 4);
    int*   cursor    = (int*)alloc(N_NODES * 4);
    int*   csr_src   = (int*)alloc(N_EDGES * 4);
    float* csr_w     = (float*)alloc(N_EDGES * 4);
    float* bufA      = (float*)alloc((size_t)N_NODES * 256 * 4);
    float* bufB      = (float*)alloc((size_t)N_NODES * 256 * 4);

    hipMemsetAsync(deg, 0, N_NODES * 4, stream);
    hipMemsetAsync(cursor, 0, N_NODES * 4, stream);

    hist_kernel<<<(N_EDGES + 255) / 256, 256, 0, stream>>>(dst, deg, N_EDGES);
    dinv_kernel<<<(N_NODES + 255) / 256, 256, 0, stream>>>(deg, dinv, N_NODES);
    scan_kernel<<<1, 1024, 0, stream>>>(deg, row_start, N_NODES);
    scatter_kernel<<<(N_EDGES + 255) / 256, 256, 0, stream>>>(src, dst, dinv, row_start, cursor,
                                                              csr_src, csr_w, N_EDGES);

    dim3 blk(256);
    // layer 1: h = x @ W1 ; h1 = relu(A_hat h + b1)
    gemm_kernel<<<dim3((N_NODES + 127) / 128, 256 / 128), blk, 0, stream>>>(x, W1, bufA, N_NODES, 256, 512);
    aggregate_kernel<4><<<(N_NODES + 3) / 4, blk, 0, stream>>>(bufA, row_start, csr_src, csr_w, dinv, b1, bufB, N_NODES);
    // layer 2
    gemm_kernel<<<dim3((N_NODES + 127) / 128, 256 / 128), blk, 0, stream>>>(bufB, W2, bufA, N_NODES, 256, 256);
    aggregate_kernel<4><<<(N_NODES + 3) / 4, blk, 0, stream>>>(bufA, row_start, csr_src, csr_w, dinv, b2, bufB, N_NODES);
    // layer 3 (128 cols)
    gemm_kernel<<<dim3((N_NODES + 127) / 128, 128 / 128), blk, 0, stream>>>(bufB, W3, bufA, N_NODES, 128, 256);
    aggregate_kernel<2><<<(N_NODES + 3) / 4, blk, 0, stream>>>(bufA, row_start, csr_src, csr_w, dinv, b3, bufB, N_NODES);
    // fused heads
    head_kernel<<<(N_NODES + 3) / 4, blk, 0, stream>>>(bufB, We, be, Wh, bh, Wg, bg, out, N_NODES);
}

// Round 5
// 781.803 us; speedup vs baseline: 1.2282x; 1.2282x over previous
//
#include <hip/hip_runtime.h>

#define N_NODES 50000
#define N_EDGES 800000
#define MP 50048   // padded rows = 391 * 128

typedef __attribute__((ext_vector_type(8))) short bf16x8;
typedef __attribute__((ext_vector_type(4))) float f32x4;

__device__ __forceinline__ unsigned short f2bf(float f) {
    unsigned u = __float_as_uint(f);
    u += 0x7fffu + ((u >> 16) & 1u);
    return (unsigned short)(u >> 16);
}
__device__ __forceinline__ float bf2f(unsigned short h) {
    return __uint_as_float(((unsigned)h) << 16);
}

// ---------------- CSR build ----------------

__global__ void hist_kernel(const int* __restrict__ dst, int* __restrict__ deg, int e) {
    int i = blockIdx.x * blockDim.x + threadIdx.x;
    if (i < e) atomicAdd(&deg[dst[i]], 1);
}

__global__ void dinv_kernel(const int* __restrict__ deg, float* __restrict__ dinv, int n) {
    int i = blockIdx.x * blockDim.x + threadIdx.x;
    if (i < n) dinv[i] = rsqrtf((float)deg[i] + 1.0f);
}

__global__ __launch_bounds__(1024) void scan_kernel(const int* __restrict__ counts,
                                                    int* __restrict__ row_start, int n) {
    __shared__ int wsum[16];
    __shared__ int carry_s;
    int tid = threadIdx.x, wid = tid >> 6, lane = tid & 63;
    if (tid == 0) carry_s = 0;
    __syncthreads();
    for (int base = 0; base < n; base += 1024) {
        int i = base + tid;
        int v = (i < n) ? counts[i] : 0;
        int s = v;
        #pragma unroll
        for (int off = 1; off < 64; off <<= 1) {
            int t = __shfl_up(s, off, 64);
            if (lane >= off) s += t;
        }
        if (lane == 63) wsum[wid] = s;
        __syncthreads();
        if (wid == 0) {
            int ws = (lane < 16) ? wsum[lane] : 0;
            #pragma unroll
            for (int off = 1; off < 16; off <<= 1) {
                int t = __shfl_up(ws, off, 64);
                if (lane >= off) ws += t;
            }
            if (lane < 16) wsum[lane] = ws;
        }
        __syncthreads();
        int carry = carry_s;
        if (i < n) row_start[i] = carry + ((wid == 0) ? 0 : wsum[wid - 1]) + s - v;
        int total = wsum[15];
        __syncthreads();
        if (tid == 0) carry_s = carry + total;
        __syncthreads();
    }
    if (tid == 0) row_start[n] = carry_s;
}

__global__ void scatter_kernel(const int* __restrict__ src, const int* __restrict__ dst,
                               const float* __restrict__ dinv,
                               const int* __restrict__ row_start, int* __restrict__ cursor,
                               int* __restrict__ csr_src, float* __restrict__ csr_w, int e) {
    int i = blockIdx.x * blockDim.x + threadIdx.x;
    if (i < e) {
        int d = dst[i], s = src[i];
        int p = atomicAdd(&cursor[d], 1);
        int idx = row_start[d] + p;
        csr_src[idx] = s;
        csr_w[idx] = dinv[s] * dinv[d];
    }
}

// ---------------- weight transpose + bf16 hi/lo split: W[K][N] -> Wt_hi/lo[N][K] ----------------

__global__ void wsplit_kernel(const float* __restrict__ W, unsigned short* __restrict__ Wh,
                              unsigned short* __restrict__ Wl, int K, int N) {
    int i = blockIdx.x * blockDim.x + threadIdx.x;
    if (i >= K * N) return;
    int k = i / N, n = i - k * N;
    float v = W[i];
    unsigned short h = f2bf(v);
    unsigned short l = f2bf(v - bf2f(h));
    Wh[(size_t)n * K + k] = h;
    Wl[(size_t)n * K + k] = l;
}

// ---------------- x -> bf16 hi/lo split (row-major, 4 elems/thread) ----------------

__global__ void xsplit_kernel(const float* __restrict__ x, unsigned short* __restrict__ Xh,
                              unsigned short* __restrict__ Xl, int total4) {
    int i = blockIdx.x * blockDim.x + threadIdx.x;
    if (i >= total4) return;
    float4 v = ((const float4*)x)[i];
    ushort4 h, l;
    h.x = f2bf(v.x); l.x = f2bf(v.x - bf2f(h.x));
    h.y = f2bf(v.y); l.y = f2bf(v.y - bf2f(h.y));
    h.z = f2bf(v.z); l.z = f2bf(v.z - bf2f(h.z));
    h.w = f2bf(v.w); l.w = f2bf(v.w - bf2f(h.w));
    ((ushort4*)Xh)[i] = h;
    ((ushort4*)Xl)[i] = l;
}

// ---------------- bf16x3 MFMA GEMM: C[M][N] = (Ah+Al)[M][K] @ (Bh+Bl)^T[N][K] ----------------
// 128x128 tile, BK=32, 4 waves (2x2), each wave 64x64 via 4x4 frags of 16x16x32 MFMA.
// LDS: 4 tiles of [128 rows][32 bf16] = 8KB each, 32KB total. Chunk-swizzled
// (slot g' = (g + (r>>1)) & 3) so ds_read_b128 is bank-conflict-free; the swizzle is
// applied on the GLOBAL source address (global_load_lds dest must stay linear, rule 21).

__global__ __launch_bounds__(256) void gemm_mfma(
    const unsigned short* __restrict__ Ah, const unsigned short* __restrict__ Al,
    const unsigned short* __restrict__ Bh, const unsigned short* __restrict__ Bl,
    float* __restrict__ C, int M, int N, int K) {
    __shared__ __align__(16) char smem[32768];
    const int tid = threadIdx.x;
    const int wid = tid >> 6, lane = tid & 63;
    const int wr = wid >> 1, wc = wid & 1;
    const int rl = lane & 15, kg = lane >> 4;
    const int bn = blockIdx.x * 128;
    const int bm = blockIdx.y * 128;
    const size_t K2 = (size_t)K * 2;   // row bytes

    // staging: 512 chunks of 16B per tile; thread handles chunks tid and tid+256
    const int c0 = tid, r0 = c0 >> 2, g10 = c0 & 3;
    const int c1 = tid + 256, r1 = c1 >> 2, g11 = c1 & 3;
    const int g0 = (g10 - (r0 >> 1)) & 3;
    const int g1 = (g11 - (r1 >> 1)) & 3;

    const char* pAh0 = (const char*)Ah + (size_t)(bm + r0) * K2 + g0 * 16;
    const char* pAh1 = (const char*)Ah + (size_t)(bm + r1) * K2 + g1 * 16;
    const char* pAl0 = (const char*)Al + (size_t)(bm + r0) * K2 + g0 * 16;
    const char* pAl1 = (const char*)Al + (size_t)(bm + r1) * K2 + g1 * 16;
    const char* pBh0 = (const char*)Bh + (size_t)(bn + r0) * K2 + g0 * 16;
    const char* pBh1 = (const char*)Bh + (size_t)(bn + r1) * K2 + g1 * 16;
    const char* pBl0 = (const char*)Bl + (size_t)(bn + r0) * K2 + g0 * 16;
    const char* pBl1 = (const char*)Bl + (size_t)(bn + r1) * K2 + g1 * 16;

    const int lds_t0 = wid * 1024;          // wave-uniform byte offsets within a tile
    const int lds_t1 = 4096 + wid * 1024;

    // read-side fragment byte offsets (within a tile)
    const int gp = (kg + (rl >> 1)) & 3;
    int offA[4], offB[4];
    #pragma unroll
    for (int m = 0; m < 4; ++m) offA[m] = (wr * 64 + m * 16 + rl) * 64 + gp * 16;
    #pragma unroll
    for (int n = 0; n < 4; ++n) offB[n] = (wc * 64 + n * 16 + rl) * 64 + gp * 16;

    f32x4 acc[4][4];
    #pragma unroll
    for (int m = 0; m < 4; ++m)
        #pragma unroll
        for (int n = 0; n < 4; ++n) acc[m][n] = (f32x4){0.f, 0.f, 0.f, 0.f};

#define GLOAD(g, loff)                                                                   \
    __builtin_amdgcn_global_load_lds((const __attribute__((address_space(1))) void*)(g), \
                                     (__attribute__((address_space(3))) void*)(smem + (loff)), \
                                     16, 0, 0)

    const int nk = K >> 5;
    for (int it = 0; it < nk; ++it) {
        const size_t kb = (size_t)it * 64;   // k0*2 bytes
        if (it) __syncthreads();
        GLOAD(pAh0 + kb, 0     + lds_t0);  GLOAD(pAh1 + kb, 0     + lds_t1);
        GLOAD(pAl0 + kb, 8192  + lds_t0);  GLOAD(pAl1 + kb, 8192  + lds_t1);
        GLOAD(pBh0 + kb, 16384 + lds_t0);  GLOAD(pBh1 + kb, 16384 + lds_t1);
        GLOAD(pBl0 + kb, 24576 + lds_t0);  GLOAD(pBl1 + kb, 24576 + lds_t1);
        __syncthreads();   // compiler emits vmcnt(0) drain before s_barrier

        bf16x8 fah[4], fal[4], fbh[4], fbl[4];
        #pragma unroll
        for (int m = 0; m < 4; ++m) {
            fah[m] = *(const bf16x8*)(smem + offA[m]);
            fal[m] = *(const bf16x8*)(smem + 8192 + offA[m]);
        }
        #pragma unroll
        for (int n = 0; n < 4; ++n) {
            fbh[n] = *(const bf16x8*)(smem + 16384 + offB[n]);
            fbl[n] = *(const bf16x8*)(smem + 24576 + offB[n]);
        }
        #pragma unroll
        for (int m = 0; m < 4; ++m)
            #pragma unroll
            for (int n = 0; n < 4; ++n) {
                acc[m][n] = __builtin_amdgcn_mfma_f32_16x16x32_bf16(fah[m], fbh[n], acc[m][n], 0, 0, 0);
                acc[m][n] = __builtin_amdgcn_mfma_f32_16x16x32_bf16(fah[m], fbl[n], acc[m][n], 0, 0, 0);
                acc[m][n] = __builtin_amdgcn_mfma_f32_16x16x32_bf16(fal[m], fbh[n], acc[m][n], 0, 0, 0);
            }
    }
#undef GLOAD

    // C/D layout: col = lane&15, row = (lane>>4)*4 + reg  [m89-verified]
    #pragma unroll
    for (int m = 0; m < 4; ++m) {
        const int rbase = bm + wr * 64 + m * 16 + kg * 4;
        #pragma unroll
        for (int n = 0; n < 4; ++n) {
            const int col = bn + wc * 64 + n * 16 + rl;
            f32x4 v = acc[m][n];
            #pragma unroll
            for (int j = 0; j < 4; ++j) {
                int row = rbase + j;
                if (row < M) C[(size_t)row * N + col] = v[j];
            }
        }
    }
}

// ---------------- aggregation: out = relu(A_hat @ hlin + bias) ----------------
// one wave per node; SPLIT writes bf16 hi/lo (feeds next MFMA GEMM), else fp32.

template <int VEC, bool SPLIT>
__global__ __launch_bounds__(256) void aggregate_kernel(
    const float* __restrict__ hlin, const int* __restrict__ row_start,
    const int* __restrict__ csr_src, const float* __restrict__ csr_w,
    const float* __restrict__ dinv, const float* __restrict__ bias,
    unsigned short* __restrict__ oh, unsigned short* __restrict__ ol,
    float* __restrict__ of, int n) {
    constexpr int COLS = 64 * VEC;
    int node = blockIdx.x * 4 + (threadIdx.x >> 6);
    int lane = threadIdx.x & 63;
    if (node >= n) return;
    int c0 = lane * VEC;

    float acc[VEC];
    float dn = dinv[node];
    float ns = dn * dn;
    {
        const float* r = hlin + (size_t)node * COLS + c0;
        if constexpr (VEC == 4) {
            float4 v = *(const float4*)r;
            acc[0] = v.x * ns; acc[1] = v.y * ns; acc[2] = v.z * ns; acc[3] = v.w * ns;
        } else {
            float2 v = *(const float2*)r;
            acc[0] = v.x * ns; acc[1] = v.y * ns;
        }
    }
    int beg = row_start[node], end = row_start[node + 1];
    int deg = end - beg;
    for (int base = 0; base < deg; base += 64) {
        int cnt = min(64, deg - base);
        int es = 0; float ew = 0.f;
        if (lane < cnt) {
            es = csr_src[beg + base + lane];
            ew = csr_w[beg + base + lane];
        }
        int i = 0;
        for (; i + 1 < cnt; i += 2) {
            int s0 = __shfl(es, i, 64);     float w0 = __shfl(ew, i, 64);
            int s1 = __shfl(es, i + 1, 64); float w1 = __shfl(ew, i + 1, 64);
            const float* r0 = hlin + (size_t)s0 * COLS + c0;
            const float* r1 = hlin + (size_t)s1 * COLS + c0;
            if constexpr (VEC == 4) {
                float4 v0 = *(const float4*)r0;
                float4 v1 = *(const float4*)r1;
                acc[0] = fmaf(w0, v0.x, acc[0]); acc[1] = fmaf(w0, v0.y, acc[1]);
                acc[2] = fmaf(w0, v0.z, acc[2]); acc[3] = fmaf(w0, v0.w, acc[3]);
                acc[0] = fmaf(w1, v1.x, acc[0]); acc[1] = fmaf(w1, v1.y, acc[1]);
                acc[2] = fmaf(w1, v1.z, acc[2]); acc[3] = fmaf(w1, v1.w, acc[3]);
            } else {
                float2 v0 = *(const float2*)r0;
                float2 v1 = *(const float2*)r1;
                acc[0] = fmaf(w0, v0.x, acc[0]); acc[1] = fmaf(w0, v0.y, acc[1]);
                acc[0] = fmaf(w1, v1.x, acc[0]); acc[1] = fmaf(w1, v1.y, acc[1]);
            }
        }
        if (i < cnt) {
            int s = __shfl(es, i, 64); float w = __shfl(ew, i, 64);
            const float* r = hlin + (size_t)s * COLS + c0;
            if constexpr (VEC == 4) {
                float4 v = *(const float4*)r;
                acc[0] = fmaf(w, v.x, acc[0]); acc[1] = fmaf(w, v.y, acc[1]);
                acc[2] = fmaf(w, v.z, acc[2]); acc[3] = fmaf(w, v.w, acc[3]);
            } else {
                float2 v = *(const float2*)r;
                acc[0] = fmaf(w, v.x, acc[0]); acc[1] = fmaf(w, v.y, acc[1]);
            }
        }
    }
    if constexpr (SPLIT) {
        unsigned short hv[VEC], lv[VEC];
        #pragma unroll
        for (int v = 0; v < VEC; ++v) {
            float val = fmaxf(acc[v] + bias[c0 + v], 0.0f);
            hv[v] = f2bf(val);
            lv[v] = f2bf(val - bf2f(hv[v]));
        }
        if constexpr (VEC == 4) {
            *(ushort4*)(oh + (size_t)node * COLS + c0) = make_ushort4(hv[0], hv[1], hv[2], hv[3]);
            *(ushort4*)(ol + (size_t)node * COLS + c0) = make_ushort4(lv[0], lv[1], lv[2], lv[3]);
        } else {
            *(ushort2*)(oh + (size_t)node * COLS + c0) = make_ushort2(hv[0], hv[1]);
            *(ushort2*)(ol + (size_t)node * COLS + c0) = make_ushort2(lv[0], lv[1]);
        }
    } else {
        #pragma unroll
        for (int v = 0; v < VEC; ++v) {
            float val = fmaxf(acc[v] + bias[c0 + v], 0.0f);
            of[(size_t)node * COLS + c0 + v] = val;
        }
    }
}

// ---------------- fused 3-head output ----------------

__global__ __launch_bounds__(256) void head_kernel(const float* __restrict__ h3,
                                                   const float* __restrict__ We, const float* __restrict__ be,
                                                   const float* __restrict__ Wh, const float* __restrict__ bh,
                                                   const float* __restrict__ Wg, const float* __restrict__ bg,
                                                   float* __restrict__ out, int n) {
    __shared__ float Ws[128][9];
    __shared__ float bs[9];
    int tid = threadIdx.x;
    for (int i = tid; i < 128 * 3; i += 256) {
        int r = i / 3, c = i % 3;
        Ws[r][c]     = We[i];
        Ws[r][c + 3] = Wh[i];
        Ws[r][c + 6] = Wg[i];
    }
    if (tid < 3) { bs[tid] = be[tid]; bs[tid + 3] = bh[tid]; bs[tid + 6] = bg[tid]; }
    __syncthreads();
    int node = blockIdx.x * 4 + (tid >> 6);
    int lane = tid & 63;
    if (node >= n) return;
    float2 v = *(const float2*)(h3 + (size_t)node * 128 + lane * 2);
    #pragma unroll
    for (int c = 0; c < 9; ++c) {
        float p = v.x * Ws[lane * 2][c] + v.y * Ws[lane * 2 + 1][c];
        #pragma unroll
        for (int m = 1; m < 64; m <<= 1) p += __shfl_xor(p, m, 64);
        if (lane == 0) out[(size_t)node * 9 + c] = p + bs[c];
    }
}

// ---------------- launch ----------------

extern "C" void kernel_launch(void* const* d_in, const int* in_sizes, int n_in,
                              void* d_out, int out_size, void* d_ws, size_t ws_size,
                              hipStream_t stream) {
    const float* x  = (const float*)d_in[0];
    const int*   ei = (const int*)d_in[1];
    const float* W1 = (const float*)d_in[2];
    const float* b1 = (const float*)d_in[3];
    const float* W2 = (const float*)d_in[4];
    const float* b2 = (const float*)d_in[5];
    const float* W3 = (const float*)d_in[6];
    const float* b3 = (const float*)d_in[7];
    const float* We = (const float*)d_in[8];
    const float* be = (const float*)d_in[9];
    const float* Wh = (const float*)d_in[10];
    const float* bh = (const float*)d_in[11];
    const float* Wg = (const float*)d_in[12];
    const float* bg = (const float*)d_in[13];
    float* out = (float*)d_out;

    const int* src = ei;
    const int* dst = ei + N_EDGES;

    char* ws = (char*)d_ws;
    size_t off = 0;
    auto alloc = [&](size_t bytes) {
        void* p = ws + off;
        off = (off + bytes + 255) & ~(size_t)255;
        return p;
    };
    int*   deg       = (int*)alloc(N_NODES * 4);
    float* dinv      = (float*)alloc(N_NODES * 4);
    int*   row_start = (int*)alloc((N_NODES + 1) * 4);
    int*   cursor    = (int*)alloc(N_NODES * 4);
    int*   csr_src   = (int*)alloc(N_EDGES * 4);
    float* csr_w     = (float*)alloc(N_EDGES * 4);
    unsigned short* Xh = (unsigned short*)alloc((size_t)MP * 512 * 2);  // later reused as H_hi [MP][256]
    unsigned short* Xl = (unsigned short*)alloc((size_t)MP * 512 * 2);  // later reused as H_lo
    float* Cbuf = (float*)alloc((size_t)MP * 256 * 4);                  // GEMM out; 2nd half doubles as h3
    unsigned short* W1h = (unsigned short*)alloc(512 * 256 * 2);
    unsigned short* W1l = (unsigned short*)alloc(512 * 256 * 2);
    unsigned short* W2h = (unsigned short*)alloc(256 * 256 * 2);
    unsigned short* W2l = (unsigned short*)alloc(256 * 256 * 2);
    unsigned short* W3h = (unsigned short*)alloc(256 * 128 * 2);
    unsigned short* W3l = (unsigned short*)alloc(256 * 128 * 2);

    unsigned short* Hh = Xh;   // aliases: x no longer needed once gemm1 is done
    unsigned short* Hl = Xl;
    float* h3 = Cbuf + (size_t)MP * 128;

    hipMemsetAsync(deg, 0, N_NODES * 4, stream);
    hipMemsetAsync(cursor, 0, N_NODES * 4, stream);

    hist_kernel<<<(N_EDGES + 255) / 256, 256, 0, stream>>>(dst, deg, N_EDGES);
    dinv_kernel<<<(N_NODES + 255) / 256, 256, 0, stream>>>(deg, dinv, N_NODES);
    scan_kernel<<<1, 1024, 0, stream>>>(deg, row_start, N_NODES);
    scatter_kernel<<<(N_EDGES + 255) / 256, 256, 0, stream>>>(src, dst, dinv, row_start, cursor,
                                                              csr_src, csr_w, N_EDGES);

    wsplit_kernel<<<(512 * 256 + 255) / 256, 256, 0, stream>>>(W1, W1h, W1l, 512, 256);
    wsplit_kernel<<<(256 * 256 + 255) / 256, 256, 0, stream>>>(W2, W2h, W2l, 256, 256);
    wsplit_kernel<<<(256 * 128 + 255) / 256, 256, 0, stream>>>(W3, W3h, W3l, 256, 128);
    xsplit_kernel<<<(N_NODES * 512 / 4 + 255) / 256, 256, 0, stream>>>(x, Xh, Xl, N_NODES * 512 / 4);

    dim3 blk(256);
    // layer 1
    gemm_mfma<<<dim3(2, MP / 128), blk, 0, stream>>>(Xh, Xl, W1h, W1l, Cbuf, N_NODES, 256, 512);
    aggregate_kernel<4, true><<<(N_NODES + 3) / 4, blk, 0, stream>>>(
        Cbuf, row_start, csr_src, csr_w, dinv, b1, Hh, Hl, nullptr, N_NODES);
    // layer 2
    gemm_mfma<<<dim3(2, MP / 128), blk, 0, stream>>>(Hh, Hl, W2h, W2l, Cbuf, N_NODES, 256, 256);
    aggregate_kernel<4, true><<<(N_NODES + 3) / 4, blk, 0, stream>>>(
        Cbuf, row_start, csr_src, csr_w, dinv, b2, Hh, Hl, nullptr, N_NODES);
    // layer 3 (N=128)
    gemm_mfma<<<dim3(1, MP / 128), blk, 0, stream>>>(Hh, Hl, W3h, W3l, Cbuf, N_NODES, 128, 256);
    aggregate_kernel<2, false><<<(N_NODES + 3) / 4, blk, 0, stream>>>(
        Cbuf, row_start, csr_src, csr_w, dinv, b3, nullptr, nullptr, h3, N_NODES);
    // fused heads
    head_kernel<<<(N_NODES + 3) / 4, blk, 0, stream>>>(h3, We, be, Wh, bh, Wg, bg, out, N_NODES);
}

// Round 9
// 626.760 us; speedup vs baseline: 1.5320x; 1.2474x over previous
//
#include <hip/hip_runtime.h>

#define N_NODES 50000
#define N_EDGES 800000
#define MP 50048   // padded rows = 391 * 128

typedef __attribute__((ext_vector_type(8))) short bf16x8;
typedef __attribute__((ext_vector_type(4))) float f32x4;
typedef _Float16 f16;
typedef __attribute__((ext_vector_type(4))) _Float16 half4;
typedef __attribute__((ext_vector_type(2))) _Float16 half2v;

__device__ __forceinline__ unsigned short f2bf(float f) {
    unsigned u = __float_as_uint(f);
    u += 0x7fffu + ((u >> 16) & 1u);
    return (unsigned short)(u >> 16);
}
__device__ __forceinline__ float bf2f(unsigned short h) {
    return __uint_as_float(((unsigned)h) << 16);
}

// ---------------- CSR build ----------------

__global__ void hist_kernel(const int* __restrict__ dst, int* __restrict__ deg, int e) {
    int i = blockIdx.x * blockDim.x + threadIdx.x;
    if (i < e) atomicAdd(&deg[dst[i]], 1);
}

__global__ void dinv_kernel(const int* __restrict__ deg, float* __restrict__ dinv, int n) {
    int i = blockIdx.x * blockDim.x + threadIdx.x;
    if (i < n) dinv[i] = rsqrtf((float)deg[i] + 1.0f);
}

__global__ __launch_bounds__(1024) void scan_kernel(const int* __restrict__ counts,
                                                    int* __restrict__ row_start, int n) {
    __shared__ int wsum[16];
    __shared__ int carry_s;
    int tid = threadIdx.x, wid = tid >> 6, lane = tid & 63;
    if (tid == 0) carry_s = 0;
    __syncthreads();
    for (int base = 0; base < n; base += 1024) {
        int i = base + tid;
        int v = (i < n) ? counts[i] : 0;
        int s = v;
        #pragma unroll
        for (int off = 1; off < 64; off <<= 1) {
            int t = __shfl_up(s, off, 64);
            if (lane >= off) s += t;
        }
        if (lane == 63) wsum[wid] = s;
        __syncthreads();
        if (wid == 0) {
            int ws = (lane < 16) ? wsum[lane] : 0;
            #pragma unroll
            for (int off = 1; off < 16; off <<= 1) {
                int t = __shfl_up(ws, off, 64);
                if (lane >= off) ws += t;
            }
            if (lane < 16) wsum[lane] = ws;
        }
        __syncthreads();
        int carry = carry_s;
        if (i < n) row_start[i] = carry + ((wid == 0) ? 0 : wsum[wid - 1]) + s - v;
        int total = wsum[15];
        __syncthreads();
        if (tid == 0) carry_s = carry + total;
        __syncthreads();
    }
    if (tid == 0) row_start[n] = carry_s;
}

__global__ void scatter_kernel(const int* __restrict__ src, const int* __restrict__ dst,
                               const float* __restrict__ dinv,
                               const int* __restrict__ row_start, int* __restrict__ cursor,
                               int* __restrict__ csr_src, float* __restrict__ csr_w, int e) {
    int i = blockIdx.x * blockDim.x + threadIdx.x;
    if (i < e) {
        int d = dst[i], s = src[i];
        int p = atomicAdd(&cursor[d], 1);
        int idx = row_start[d] + p;
        csr_src[idx] = s;
        csr_w[idx] = dinv[s] * dinv[d];
    }
}

// ---------------- weight transpose + bf16 hi/lo split: W[K][N] -> Wt_hi/lo[N][K] ----------------

__global__ void wsplit_kernel(const float* __restrict__ W, unsigned short* __restrict__ Wh,
                              unsigned short* __restrict__ Wl, int K, int N) {
    int i = blockIdx.x * blockDim.x + threadIdx.x;
    if (i >= K * N) return;
    int k = i / N, n = i - k * N;
    float v = W[i];
    unsigned short h = f2bf(v);
    unsigned short l = f2bf(v - bf2f(h));
    Wh[(size_t)n * K + k] = h;
    Wl[(size_t)n * K + k] = l;
}

// ---------------- x -> bf16 hi/lo split ----------------

__global__ void xsplit_kernel(const float* __restrict__ x, unsigned short* __restrict__ Xh,
                              unsigned short* __restrict__ Xl, int total4) {
    int i = blockIdx.x * blockDim.x + threadIdx.x;
    if (i >= total4) return;
    float4 v = ((const float4*)x)[i];
    ushort4 h, l;
    h.x = f2bf(v.x); l.x = f2bf(v.x - bf2f(h.x));
    h.y = f2bf(v.y); l.y = f2bf(v.y - bf2f(h.y));
    h.z = f2bf(v.z); l.z = f2bf(v.z - bf2f(h.z));
    h.w = f2bf(v.w); l.w = f2bf(v.w - bf2f(h.w));
    ((ushort4*)Xh)[i] = h;
    ((ushort4*)Xl)[i] = l;
}

// ---------------- bf16x3 MFMA GEMM: C[M][N] = (Ah+Al)[M][K] @ (Bh+Bl)^T[N][K], fp16 out ----------------
// 128x128 tile, BK=32, 4 waves (2x2), each wave 64x64 via 4x4 frags of 16x16x32 MFMA.
// Chunk-swizzle applied on GLOBAL source (global_load_lds dest linear, rule 21); read-side
// uses the same involution -> ds_read_b128 conflict-free.

__global__ __launch_bounds__(256) void gemm_mfma(
    const unsigned short* __restrict__ Ah, const unsigned short* __restrict__ Al,
    const unsigned short* __restrict__ Bh, const unsigned short* __restrict__ Bl,
    f16* __restrict__ C, int M, int N, int K) {
    __shared__ __align__(16) char smem[32768];
    const int tid = threadIdx.x;
    const int wid = tid >> 6, lane = tid & 63;
    const int wr = wid >> 1, wc = wid & 1;
    const int rl = lane & 15, kg = lane >> 4;
    const int bn = blockIdx.x * 128;
    const int bm = blockIdx.y * 128;
    const size_t K2 = (size_t)K * 2;   // row bytes

    const int c0 = tid, r0 = c0 >> 2, g10 = c0 & 3;
    const int c1 = tid + 256, r1 = c1 >> 2, g11 = c1 & 3;
    const int g0 = (g10 - (r0 >> 1)) & 3;
    const int g1 = (g11 - (r1 >> 1)) & 3;

    const char* pAh0 = (const char*)Ah + (size_t)(bm + r0) * K2 + g0 * 16;
    const char* pAh1 = (const char*)Ah + (size_t)(bm + r1) * K2 + g1 * 16;
    const char* pAl0 = (const char*)Al + (size_t)(bm + r0) * K2 + g0 * 16;
    const char* pAl1 = (const char*)Al + (size_t)(bm + r1) * K2 + g1 * 16;
    const char* pBh0 = (const char*)Bh + (size_t)(bn + r0) * K2 + g0 * 16;
    const char* pBh1 = (const char*)Bh + (size_t)(bn + r1) * K2 + g1 * 16;
    const char* pBl0 = (const char*)Bl + (size_t)(bn + r0) * K2 + g0 * 16;
    const char* pBl1 = (const char*)Bl + (size_t)(bn + r1) * K2 + g1 * 16;

    const int lds_t0 = wid * 1024;
    const int lds_t1 = 4096 + wid * 1024;

    const int gp = (kg + (rl >> 1)) & 3;
    int offA[4], offB[4];
    #pragma unroll
    for (int m = 0; m < 4; ++m) offA[m] = (wr * 64 + m * 16 + rl) * 64 + gp * 16;
    #pragma unroll
    for (int n = 0; n < 4; ++n) offB[n] = (wc * 64 + n * 16 + rl) * 64 + gp * 16;

    f32x4 acc[4][4];
    #pragma unroll
    for (int m = 0; m < 4; ++m)
        #pragma unroll
        for (int n = 0; n < 4; ++n) acc[m][n] = (f32x4){0.f, 0.f, 0.f, 0.f};

#define GLOAD(g, loff)                                                                   \
    __builtin_amdgcn_global_load_lds((const __attribute__((address_space(1))) void*)(g), \
                                     (__attribute__((address_space(3))) void*)(smem + (loff)), \
                                     16, 0, 0)

    const int nk = K >> 5;
    for (int it = 0; it < nk; ++it) {
        const size_t kb = (size_t)it * 64;
        if (it) __syncthreads();
        GLOAD(pAh0 + kb, 0     + lds_t0);  GLOAD(pAh1 + kb, 0     + lds_t1);
        GLOAD(pAl0 + kb, 8192  + lds_t0);  GLOAD(pAl1 + kb, 8192  + lds_t1);
        GLOAD(pBh0 + kb, 16384 + lds_t0);  GLOAD(pBh1 + kb, 16384 + lds_t1);
        GLOAD(pBl0 + kb, 24576 + lds_t0);  GLOAD(pBl1 + kb, 24576 + lds_t1);
        __syncthreads();

        bf16x8 fah[4], fal[4], fbh[4], fbl[4];
        #pragma unroll
        for (int m = 0; m < 4; ++m) {
            fah[m] = *(const bf16x8*)(smem + offA[m]);
            fal[m] = *(const bf16x8*)(smem + 8192 + offA[m]);
        }
        #pragma unroll
        for (int n = 0; n < 4; ++n) {
            fbh[n] = *(const bf16x8*)(smem + 16384 + offB[n]);
            fbl[n] = *(const bf16x8*)(smem + 24576 + offB[n]);
        }
        #pragma unroll
        for (int m = 0; m < 4; ++m)
            #pragma unroll
            for (int n = 0; n < 4; ++n) {
                acc[m][n] = __builtin_amdgcn_mfma_f32_16x16x32_bf16(fah[m], fbh[n], acc[m][n], 0, 0, 0);
                acc[m][n] = __builtin_amdgcn_mfma_f32_16x16x32_bf16(fah[m], fbl[n], acc[m][n], 0, 0, 0);
                acc[m][n] = __builtin_amdgcn_mfma_f32_16x16x32_bf16(fal[m], fbh[n], acc[m][n], 0, 0, 0);
            }
    }
#undef GLOAD

    // C/D layout: col = lane&15, row = (lane>>4)*4 + reg  [m89-verified]
    #pragma unroll
    for (int m = 0; m < 4; ++m) {
        const int rbase = bm + wr * 64 + m * 16 + kg * 4;
        #pragma unroll
        for (int n = 0; n < 4; ++n) {
            const int col = bn + wc * 64 + n * 16 + rl;
            f32x4 v = acc[m][n];
            #pragma unroll
            for (int j = 0; j < 4; ++j) {
                int row = rbase + j;
                if (row < M) C[(size_t)row * N + col] = (f16)v[j];
            }
        }
    }
}

// ---------------- aggregation (256 cols): bf16 hi/lo out = relu(A_hat @ hlin + bias) ----------------
// one wave per node; gathers fp16 rows (half the bytes of fp32), fp32 accumulate.

__global__ __launch_bounds__(256) void aggregate4_kernel(
    const f16* __restrict__ hlin, const int* __restrict__ row_start,
    const int* __restrict__ csr_src, const float* __restrict__ csr_w,
    const float* __restrict__ dinv, const float* __restrict__ bias,
    unsigned short* __restrict__ oh, unsigned short* __restrict__ ol, int n) {
    constexpr int COLS = 256;
    int node = blockIdx.x * 4 + (threadIdx.x >> 6);
    int lane = threadIdx.x & 63;
    if (node >= n) return;
    int c0 = lane * 4;

    float acc[4];
    float dn = dinv[node];
    float ns = dn * dn;
    {
        half4 v = *(const half4*)(hlin + (size_t)node * COLS + c0);
        #pragma unroll
        for (int k = 0; k < 4; ++k) acc[k] = (float)v[k] * ns;
    }
    int beg = row_start[node], end = row_start[node + 1];
    int deg = end - beg;
    for (int base = 0; base < deg; base += 64) {
        int cnt = min(64, deg - base);
        int es = 0; float ew = 0.f;
        if (lane < cnt) {
            es = csr_src[beg + base + lane];
            ew = csr_w[beg + base + lane];
        }
        int i = 0;
        for (; i + 1 < cnt; i += 2) {
            int s0 = __shfl(es, i, 64);     float w0 = __shfl(ew, i, 64);
            int s1 = __shfl(es, i + 1, 64); float w1 = __shfl(ew, i + 1, 64);
            half4 v0 = *(const half4*)(hlin + (size_t)s0 * COLS + c0);
            half4 v1 = *(const half4*)(hlin + (size_t)s1 * COLS + c0);
            #pragma unroll
            for (int k = 0; k < 4; ++k) acc[k] = fmaf(w0, (float)v0[k], acc[k]);
            #pragma unroll
            for (int k = 0; k < 4; ++k) acc[k] = fmaf(w1, (float)v1[k], acc[k]);
        }
        if (i < cnt) {
            int s = __shfl(es, i, 64); float w = __shfl(ew, i, 64);
            half4 v = *(const half4*)(hlin + (size_t)s * COLS + c0);
            #pragma unroll
            for (int k = 0; k < 4; ++k) acc[k] = fmaf(w, (float)v[k], acc[k]);
        }
    }
    unsigned short hv[4], lv[4];
    #pragma unroll
    for (int v = 0; v < 4; ++v) {
        float val = fmaxf(acc[v] + bias[c0 + v], 0.0f);
        hv[v] = f2bf(val);
        lv[v] = f2bf(val - bf2f(hv[v]));
    }
    *(ushort4*)(oh + (size_t)node * COLS + c0) = make_ushort4(hv[0], hv[1], hv[2], hv[3]);
    *(ushort4*)(ol + (size_t)node * COLS + c0) = make_ushort4(lv[0], lv[1], lv[2], lv[3]);
}

// ---------------- fused layer-3 aggregation (128 cols) + 3-head output ----------------
// h3 row stays in wave registers; 9 output cols via shfl-reduce. No h3 materialization.

__global__ __launch_bounds__(256) void agg_head_kernel(
    const f16* __restrict__ hlin, const int* __restrict__ row_start,
    const int* __restrict__ csr_src, const float* __restrict__ csr_w,
    const float* __restrict__ dinv, const float* __restrict__ bias,
    const float* __restrict__ We, const float* __restrict__ be,
    const float* __restrict__ Wh, const float* __restrict__ bh,
    const float* __restrict__ Wg, const float* __restrict__ bg,
    float* __restrict__ out, int n) {
    constexpr int COLS = 128;
    __shared__ float Ws[128][9];
    __shared__ float bs[9];
    int tid = threadIdx.x;
    for (int i = tid; i < 128 * 3; i += 256) {
        int r = i / 3, c = i % 3;
        Ws[r][c]     = We[i];
        Ws[r][c + 3] = Wh[i];
        Ws[r][c + 6] = Wg[i];
    }
    if (tid < 3) { bs[tid] = be[tid]; bs[tid + 3] = bh[tid]; bs[tid + 6] = bg[tid]; }
    __syncthreads();

    int node = blockIdx.x * 4 + (tid >> 6);
    int lane = tid & 63;
    if (node >= n) return;
    int c0 = lane * 2;

    float acc0, acc1;
    float dn = dinv[node];
    float ns = dn * dn;
    {
        half2v v = *(const half2v*)(hlin + (size_t)node * COLS + c0);
        acc0 = (float)v[0] * ns; acc1 = (float)v[1] * ns;
    }
    int beg = row_start[node], end = row_start[node + 1];
    int deg = end - beg;
    for (int base = 0; base < deg; base += 64) {
        int cnt = min(64, deg - base);
        int es = 0; float ew = 0.f;
        if (lane < cnt) {
            es = csr_src[beg + base + lane];
            ew = csr_w[beg + base + lane];
        }
        int i = 0;
        for (; i + 1 < cnt; i += 2) {
            int s0 = __shfl(es, i, 64);     float w0 = __shfl(ew, i, 64);
            int s1 = __shfl(es, i + 1, 64); float w1 = __shfl(ew, i + 1, 64);
            half2v v0 = *(const half2v*)(hlin + (size_t)s0 * COLS + c0);
            half2v v1 = *(const half2v*)(hlin + (size_t)s1 * COLS + c0);
            acc0 = fmaf(w0, (float)v0[0], acc0); acc1 = fmaf(w0, (float)v0[1], acc1);
            acc0 = fmaf(w1, (float)v1[0], acc0); acc1 = fmaf(w1, (float)v1[1], acc1);
        }
        if (i < cnt) {
            int s = __shfl(es, i, 64); float w = __shfl(ew, i, 64);
            half2v v = *(const half2v*)(hlin + (size_t)s * COLS + c0);
            acc0 = fmaf(w, (float)v[0], acc0); acc1 = fmaf(w, (float)v[1], acc1);
        }
    }
    float h0 = fmaxf(acc0 + bias[c0], 0.0f);
    float h1 = fmaxf(acc1 + bias[c0 + 1], 0.0f);
    #pragma unroll
    for (int c = 0; c < 9; ++c) {
        float p = h0 * Ws[c0][c] + h1 * Ws[c0 + 1][c];
        #pragma unroll
        for (int m = 1; m < 64; m <<= 1) p += __shfl_xor(p, m, 64);
        if (lane == 0) out[(size_t)node * 9 + c] = p + bs[c];
    }
}

// ---------------- launch ----------------

extern "C" void kernel_launch(void* const* d_in, const int* in_sizes, int n_in,
                              void* d_out, int out_size, void* d_ws, size_t ws_size,
                              hipStream_t stream) {
    const float* x  = (const float*)d_in[0];
    const int*   ei = (const int*)d_in[1];
    const float* W1 = (const float*)d_in[2];
    const float* b1 = (const float*)d_in[3];
    const float* W2 = (const float*)d_in[4];
    const float* b2 = (const float*)d_in[5];
    const float* W3 = (const float*)d_in[6];
    const float* b3 = (const float*)d_in[7];
    const float* We = (const float*)d_in[8];
    const float* be = (const float*)d_in[9];
    const float* Wh = (const float*)d_in[10];
    const float* bh = (const float*)d_in[11];
    const float* Wg = (const float*)d_in[12];
    const float* bg = (const float*)d_in[13];
    float* out = (float*)d_out;

    const int* src = ei;
    const int* dst = ei + N_EDGES;

    char* ws = (char*)d_ws;
    size_t off = 0;
    auto alloc = [&](size_t bytes) {
        void* p = ws + off;
        off = (off + bytes + 255) & ~(size_t)255;
        return p;
    };
    int*   deg       = (int*)alloc(N_NODES * 4);
    float* dinv      = (float*)alloc(N_NODES * 4);
    int*   row_start = (int*)alloc((N_NODES + 1) * 4);
    int*   cursor    = (int*)alloc(N_NODES * 4);
    int*   csr_src   = (int*)alloc(N_EDGES * 4);
    float* csr_w     = (float*)alloc(N_EDGES * 4);
    unsigned short* Xh = (unsigned short*)alloc((size_t)MP * 512 * 2);  // reused as H_hi [MP][256]
    unsigned short* Xl = (unsigned short*)alloc((size_t)MP * 512 * 2);  // reused as H_lo
    f16* Cbuf = (f16*)alloc((size_t)MP * 256 * 2);                      // fp16 GEMM out (gather table)
    unsigned short* W1h = (unsigned short*)alloc(512 * 256 * 2);
    unsigned short* W1l = (unsigned short*)alloc(512 * 256 * 2);
    unsigned short* W2h = (unsigned short*)alloc(256 * 256 * 2);
    unsigned short* W2l = (unsigned short*)alloc(256 * 256 * 2);
    unsigned short* W3h = (unsigned short*)alloc(256 * 128 * 2);
    unsigned short* W3l = (unsigned short*)alloc(256 * 128 * 2);

    unsigned short* Hh = Xh;   // x no longer needed once gemm1 is done
    unsigned short* Hl = Xl;

    hipMemsetAsync(deg, 0, N_NODES * 4, stream);
    hipMemsetAsync(cursor, 0, N_NODES * 4, stream);

    hist_kernel<<<(N_EDGES + 255) / 256, 256, 0, stream>>>(dst, deg, N_EDGES);
    dinv_kernel<<<(N_NODES + 255) / 256, 256, 0, stream>>>(deg, dinv, N_NODES);
    scan_kernel<<<1, 1024, 0, stream>>>(deg, row_start, N_NODES);
    scatter_kernel<<<(N_EDGES + 255) / 256, 256, 0, stream>>>(src, dst, dinv, row_start, cursor,
                                                              csr_src, csr_w, N_EDGES);

    wsplit_kernel<<<(512 * 256 + 255) / 256, 256, 0, stream>>>(W1, W1h, W1l, 512, 256);
    wsplit_kernel<<<(256 * 256 + 255) / 256, 256, 0, stream>>>(W2, W2h, W2l, 256, 256);
    wsplit_kernel<<<(256 * 128 + 255) / 256, 256, 0, stream>>>(W3, W3h, W3l, 256, 128);
    xsplit_kernel<<<(N_NODES * 512 / 4 + 255) / 256, 256, 0, stream>>>(x, Xh, Xl, N_NODES * 512 / 4);

    dim3 blk(256);
    // layer 1
    gemm_mfma<<<dim3(2, MP / 128), blk, 0, stream>>>(Xh, Xl, W1h, W1l, Cbuf, N_NODES, 256, 512);
    aggregate4_kernel<<<(N_NODES + 3) / 4, blk, 0, stream>>>(
        Cbuf, row_start, csr_src, csr_w, dinv, b1, Hh, Hl, N_NODES);
    // layer 2
    gemm_mfma<<<dim3(2, MP / 128), blk, 0, stream>>>(Hh, Hl, W2h, W2l, Cbuf, N_NODES, 256, 256);
    aggregate4_kernel<<<(N_NODES + 3) / 4, blk, 0, stream>>>(
        Cbuf, row_start, csr_src, csr_w, dinv, b2, Hh, Hl, N_NODES);
    // layer 3 (N=128) + fused heads
    gemm_mfma<<<dim3(1, MP / 128), blk, 0, stream>>>(Hh, Hl, W3h, W3l, Cbuf, N_NODES, 128, 256);
    agg_head_kernel<<<(N_NODES + 3) / 4, blk, 0, stream>>>(
        Cbuf, row_start, csr_src, csr_w, dinv, b3, We, be, Wh, bh, Wg, bg, out, N_NODES);
}

// Round 10
// 617.957 us; speedup vs baseline: 1.5538x; 1.0142x over previous
//
#include <hip/hip_runtime.h>

#define N_NODES 50000
#define N_EDGES 800000
#define MP 50048   // padded rows = 391 * 128

typedef __attribute__((ext_vector_type(8))) short bf16x8;
typedef __attribute__((ext_vector_type(4))) float f32x4;
typedef _Float16 f16;
typedef __attribute__((ext_vector_type(4))) _Float16 half4;
typedef __attribute__((ext_vector_type(2))) _Float16 half2v;

__device__ __forceinline__ unsigned short f2bf(float f) {
    unsigned u = __float_as_uint(f);
    u += 0x7fffu + ((u >> 16) & 1u);
    return (unsigned short)(u >> 16);
}
__device__ __forceinline__ float bf2f(unsigned short h) {
    return __uint_as_float(((unsigned)h) << 16);
}

// ---------------- CSR build ----------------

__global__ void hist_kernel(const int* __restrict__ dst, int* __restrict__ deg, int e) {
    int i = blockIdx.x * blockDim.x + threadIdx.x;
    if (i < e) atomicAdd(&deg[dst[i]], 1);
}

__global__ void dinv_kernel(const int* __restrict__ deg, float* __restrict__ dinv, int n) {
    int i = blockIdx.x * blockDim.x + threadIdx.x;
    if (i < n) dinv[i] = rsqrtf((float)deg[i] + 1.0f);
}

__global__ __launch_bounds__(1024) void scan_kernel(const int* __restrict__ counts,
                                                    int* __restrict__ row_start, int n) {
    __shared__ int wsum[16];
    __shared__ int carry_s;
    int tid = threadIdx.x, wid = tid >> 6, lane = tid & 63;
    if (tid == 0) carry_s = 0;
    __syncthreads();
    for (int base = 0; base < n; base += 1024) {
        int i = base + tid;
        int v = (i < n) ? counts[i] : 0;
        int s = v;
        #pragma unroll
        for (int off = 1; off < 64; off <<= 1) {
            int t = __shfl_up(s, off, 64);
            if (lane >= off) s += t;
        }
        if (lane == 63) wsum[wid] = s;
        __syncthreads();
        if (wid == 0) {
            int ws = (lane < 16) ? wsum[lane] : 0;
            #pragma unroll
            for (int off = 1; off < 16; off <<= 1) {
                int t = __shfl_up(ws, off, 64);
                if (lane >= off) ws += t;
            }
            if (lane < 16) wsum[lane] = ws;
        }
        __syncthreads();
        int carry = carry_s;
        if (i < n) row_start[i] = carry + ((wid == 0) ? 0 : wsum[wid - 1]) + s - v;
        int total = wsum[15];
        __syncthreads();
        if (tid == 0) carry_s = carry + total;
        __syncthreads();
    }
    if (tid == 0) row_start[n] = carry_s;
}

__global__ void scatter_kernel(const int* __restrict__ src, const int* __restrict__ dst,
                               const float* __restrict__ dinv,
                               const int* __restrict__ row_start, int* __restrict__ cursor,
                               int* __restrict__ csr_src, float* __restrict__ csr_w, int e) {
    int i = blockIdx.x * blockDim.x + threadIdx.x;
    if (i < e) {
        int d = dst[i], s = src[i];
        int p = atomicAdd(&cursor[d], 1);
        int idx = row_start[d] + p;
        csr_src[idx] = s;
        csr_w[idx] = dinv[s] * dinv[d];
    }
}

// ---------------- weight transpose + bf16 hi/lo split: W[K][N] -> Wt_hi/lo[N][K] ----------------

__global__ void wsplit_kernel(const float* __restrict__ W, unsigned short* __restrict__ Wh,
                              unsigned short* __restrict__ Wl, int K, int N) {
    int i = blockIdx.x * blockDim.x + threadIdx.x;
    if (i >= K * N) return;
    int k = i / N, n = i - k * N;
    float v = W[i];
    unsigned short h = f2bf(v);
    unsigned short l = f2bf(v - bf2f(h));
    Wh[(size_t)n * K + k] = h;
    Wl[(size_t)n * K + k] = l;
}

// ---------------- x -> bf16 hi/lo split ----------------

__global__ void xsplit_kernel(const float* __restrict__ x, unsigned short* __restrict__ Xh,
                              unsigned short* __restrict__ Xl, int total4) {
    int i = blockIdx.x * blockDim.x + threadIdx.x;
    if (i >= total4) return;
    float4 v = ((const float4*)x)[i];
    ushort4 h, l;
    h.x = f2bf(v.x); l.x = f2bf(v.x - bf2f(h.x));
    h.y = f2bf(v.y); l.y = f2bf(v.y - bf2f(h.y));
    h.z = f2bf(v.z); l.z = f2bf(v.z - bf2f(h.z));
    h.w = f2bf(v.w); l.w = f2bf(v.w - bf2f(h.w));
    ((ushort4*)Xh)[i] = h;
    ((ushort4*)Xl)[i] = l;
}

// ---------------- bf16x3 MFMA GEMM: C[M][N] = (Ah+Al)[M][K] @ (Bh+Bl)^T[N][K], fp16 out ----------------
// 128x128 tile, BK=32, 4 waves (2x2), each wave 64x64 via 4x4 frags of 16x16x32 MFMA.
// Chunk-swizzle applied on GLOBAL source (global_load_lds dest linear, rule 21); read-side
// uses the same involution -> ds_read_b128 conflict-free.

__global__ __launch_bounds__(256) void gemm_mfma(
    const unsigned short* __restrict__ Ah, const unsigned short* __restrict__ Al,
    const unsigned short* __restrict__ Bh, const unsigned short* __restrict__ Bl,
    f16* __restrict__ C, int M, int N, int K) {
    __shared__ __align__(16) char smem[32768];
    const int tid = threadIdx.x;
    const int wid = tid >> 6, lane = tid & 63;
    const int wr = wid >> 1, wc = wid & 1;
    const int rl = lane & 15, kg = lane >> 4;
    const int bn = blockIdx.x * 128;
    const int bm = blockIdx.y * 128;
    const size_t K2 = (size_t)K * 2;   // row bytes

    const int c0 = tid, r0 = c0 >> 2, g10 = c0 & 3;
    const int c1 = tid + 256, r1 = c1 >> 2, g11 = c1 & 3;
    const int g0 = (g10 - (r0 >> 1)) & 3;
    const int g1 = (g11 - (r1 >> 1)) & 3;

    const char* pAh0 = (const char*)Ah + (size_t)(bm + r0) * K2 + g0 * 16;
    const char* pAh1 = (const char*)Ah + (size_t)(bm + r1) * K2 + g1 * 16;
    const char* pAl0 = (const char*)Al + (size_t)(bm + r0) * K2 + g0 * 16;
    const char* pAl1 = (const char*)Al + (size_t)(bm + r1) * K2 + g1 * 16;
    const char* pBh0 = (const char*)Bh + (size_t)(bn + r0) * K2 + g0 * 16;
    const char* pBh1 = (const char*)Bh + (size_t)(bn + r1) * K2 + g1 * 16;
    const char* pBl0 = (const char*)Bl + (size_t)(bn + r0) * K2 + g0 * 16;
    const char* pBl1 = (const char*)Bl + (size_t)(bn + r1) * K2 + g1 * 16;

    const int lds_t0 = wid * 1024;
    const int lds_t1 = 4096 + wid * 1024;

    const int gp = (kg + (rl >> 1)) & 3;
    int offA[4], offB[4];
    #pragma unroll
    for (int m = 0; m < 4; ++m) offA[m] = (wr * 64 + m * 16 + rl) * 64 + gp * 16;
    #pragma unroll
    for (int n = 0; n < 4; ++n) offB[n] = (wc * 64 + n * 16 + rl) * 64 + gp * 16;

    f32x4 acc[4][4];
    #pragma unroll
    for (int m = 0; m < 4; ++m)
        #pragma unroll
        for (int n = 0; n < 4; ++n) acc[m][n] = (f32x4){0.f, 0.f, 0.f, 0.f};

#define GLOAD(g, loff)                                                                   \
    __builtin_amdgcn_global_load_lds((const __attribute__((address_space(1))) void*)(g), \
                                     (__attribute__((address_space(3))) void*)(smem + (loff)), \
                                     16, 0, 0)

    const int nk = K >> 5;
    for (int it = 0; it < nk; ++it) {
        const size_t kb = (size_t)it * 64;
        if (it) __syncthreads();
        GLOAD(pAh0 + kb, 0     + lds_t0);  GLOAD(pAh1 + kb, 0     + lds_t1);
        GLOAD(pAl0 + kb, 8192  + lds_t0);  GLOAD(pAl1 + kb, 8192  + lds_t1);
        GLOAD(pBh0 + kb, 16384 + lds_t0);  GLOAD(pBh1 + kb, 16384 + lds_t1);
        GLOAD(pBl0 + kb, 24576 + lds_t0);  GLOAD(pBl1 + kb, 24576 + lds_t1);
        __syncthreads();

        bf16x8 fah[4], fal[4], fbh[4], fbl[4];
        #pragma unroll
        for (int m = 0; m < 4; ++m) {
            fah[m] = *(const bf16x8*)(smem + offA[m]);
            fal[m] = *(const bf16x8*)(smem + 8192 + offA[m]);
        }
        #pragma unroll
        for (int n = 0; n < 4; ++n) {
            fbh[n] = *(const bf16x8*)(smem + 16384 + offB[n]);
            fbl[n] = *(const bf16x8*)(smem + 24576 + offB[n]);
        }
        #pragma unroll
        for (int m = 0; m < 4; ++m)
            #pragma unroll
            for (int n = 0; n < 4; ++n) {
                acc[m][n] = __builtin_amdgcn_mfma_f32_16x16x32_bf16(fah[m], fbh[n], acc[m][n], 0, 0, 0);
                acc[m][n] = __builtin_amdgcn_mfma_f32_16x16x32_bf16(fah[m], fbl[n], acc[m][n], 0, 0, 0);
                acc[m][n] = __builtin_amdgcn_mfma_f32_16x16x32_bf16(fal[m], fbh[n], acc[m][n], 0, 0, 0);
            }
    }
#undef GLOAD

    // C/D layout: col = lane&15, row = (lane>>4)*4 + reg  [m89-verified]
    #pragma unroll
    for (int m = 0; m < 4; ++m) {
        const int rbase = bm + wr * 64 + m * 16 + kg * 4;
        #pragma unroll
        for (int n = 0; n < 4; ++n) {
            const int col = bn + wc * 64 + n * 16 + rl;
            f32x4 v = acc[m][n];
            #pragma unroll
            for (int j = 0; j < 4; ++j) {
                int row = rbase + j;
                if (row < M) C[(size_t)row * N + col] = (f16)v[j];
            }
        }
    }
}

// ---------------- aggregation (256 cols): bf16 hi/lo out = relu(A_hat @ hlin + bias) ----------------
// one wave per node; fp16 gathers, fp32 accumulate. 8-edge unroll: 8 independent
// row-gathers in flight per wave (latency-bound fix; was 2).

__global__ __launch_bounds__(256) void aggregate4_kernel(
    const f16* __restrict__ hlin, const int* __restrict__ row_start,
    const int* __restrict__ csr_src, const float* __restrict__ csr_w,
    const float* __restrict__ dinv, const float* __restrict__ bias,
    unsigned short* __restrict__ oh, unsigned short* __restrict__ ol, int n) {
    constexpr int COLS = 256;
    int node = blockIdx.x * 4 + (threadIdx.x >> 6);
    int lane = threadIdx.x & 63;
    if (node >= n) return;
    int c0 = lane * 4;

    float acc[4];
    float dn = dinv[node];
    float ns = dn * dn;
    {
        half4 v = *(const half4*)(hlin + (size_t)node * COLS + c0);
        #pragma unroll
        for (int k = 0; k < 4; ++k) acc[k] = (float)v[k] * ns;
    }
    int beg = row_start[node], end = row_start[node + 1];
    int deg = end - beg;
    for (int base = 0; base < deg; base += 64) {
        int cnt = min(64, deg - base);
        int es = 0; float ew = 0.f;
        if (lane < cnt) {
            es = csr_src[beg + base + lane];
            ew = csr_w[beg + base + lane];
        }
        int i = 0;
        for (; i + 8 <= cnt; i += 8) {
            int ss[8]; float ww[8]; half4 vv[8];
            #pragma unroll
            for (int j = 0; j < 8; ++j) {
                ss[j] = __shfl(es, i + j, 64);
                ww[j] = __shfl(ew, i + j, 64);
            }
            #pragma unroll
            for (int j = 0; j < 8; ++j)
                vv[j] = *(const half4*)(hlin + (size_t)ss[j] * COLS + c0);
            #pragma unroll
            for (int j = 0; j < 8; ++j)
                #pragma unroll
                for (int k = 0; k < 4; ++k) acc[k] = fmaf(ww[j], (float)vv[j][k], acc[k]);
        }
        for (; i + 2 <= cnt; i += 2) {
            int s0 = __shfl(es, i, 64);     float w0 = __shfl(ew, i, 64);
            int s1 = __shfl(es, i + 1, 64); float w1 = __shfl(ew, i + 1, 64);
            half4 v0 = *(const half4*)(hlin + (size_t)s0 * COLS + c0);
            half4 v1 = *(const half4*)(hlin + (size_t)s1 * COLS + c0);
            #pragma unroll
            for (int k = 0; k < 4; ++k) acc[k] = fmaf(w0, (float)v0[k], acc[k]);
            #pragma unroll
            for (int k = 0; k < 4; ++k) acc[k] = fmaf(w1, (float)v1[k], acc[k]);
        }
        if (i < cnt) {
            int s = __shfl(es, i, 64); float w = __shfl(ew, i, 64);
            half4 v = *(const half4*)(hlin + (size_t)s * COLS + c0);
            #pragma unroll
            for (int k = 0; k < 4; ++k) acc[k] = fmaf(w, (float)v[k], acc[k]);
        }
    }
    unsigned short hv[4], lv[4];
    #pragma unroll
    for (int v = 0; v < 4; ++v) {
        float val = fmaxf(acc[v] + bias[c0 + v], 0.0f);
        hv[v] = f2bf(val);
        lv[v] = f2bf(val - bf2f(hv[v]));
    }
    *(ushort4*)(oh + (size_t)node * COLS + c0) = make_ushort4(hv[0], hv[1], hv[2], hv[3]);
    *(ushort4*)(ol + (size_t)node * COLS + c0) = make_ushort4(lv[0], lv[1], lv[2], lv[3]);
}

// ---------------- fused layer-3 aggregation (128 cols) + 3-head output ----------------
// h3 row stays in wave registers; 9 output cols via shfl-reduce. 8-edge unroll.
// Ws stored TRANSPOSED [9][130]: lane reads consecutive floats -> 2-way aliasing (free),
// vs old [128][9] where lanes 16 apart always hit the same bank (4-way, 2.25M conflicts).

__global__ __launch_bounds__(256) void agg_head_kernel(
    const f16* __restrict__ hlin, const int* __restrict__ row_start,
    const int* __restrict__ csr_src, const float* __restrict__ csr_w,
    const float* __restrict__ dinv, const float* __restrict__ bias,
    const float* __restrict__ We, const float* __restrict__ be,
    const float* __restrict__ Wh, const float* __restrict__ bh,
    const float* __restrict__ Wg, const float* __restrict__ bg,
    float* __restrict__ out, int n) {
    constexpr int COLS = 128;
    __shared__ float Ws[9][130];
    __shared__ float bs[9];
    int tid = threadIdx.x;
    for (int i = tid; i < 128 * 3; i += 256) {
        int r = i / 3, c = i % 3;
        Ws[c][r]     = We[i];
        Ws[c + 3][r] = Wh[i];
        Ws[c + 6][r] = Wg[i];
    }
    if (tid < 3) { bs[tid] = be[tid]; bs[tid + 3] = bh[tid]; bs[tid + 6] = bg[tid]; }
    __syncthreads();

    int node = blockIdx.x * 4 + (tid >> 6);
    int lane = tid & 63;
    if (node >= n) return;
    int c0 = lane * 2;

    float acc0, acc1;
    float dn = dinv[node];
    float ns = dn * dn;
    {
        half2v v = *(const half2v*)(hlin + (size_t)node * COLS + c0);
        acc0 = (float)v[0] * ns; acc1 = (float)v[1] * ns;
    }
    int beg = row_start[node], end = row_start[node + 1];
    int deg = end - beg;
    for (int base = 0; base < deg; base += 64) {
        int cnt = min(64, deg - base);
        int es = 0; float ew = 0.f;
        if (lane < cnt) {
            es = csr_src[beg + base + lane];
            ew = csr_w[beg + base + lane];
        }
        int i = 0;
        for (; i + 8 <= cnt; i += 8) {
            int ss[8]; float ww[8]; half2v vv[8];
            #pragma unroll
            for (int j = 0; j < 8; ++j) {
                ss[j] = __shfl(es, i + j, 64);
                ww[j] = __shfl(ew, i + j, 64);
            }
            #pragma unroll
            for (int j = 0; j < 8; ++j)
                vv[j] = *(const half2v*)(hlin + (size_t)ss[j] * COLS + c0);
            #pragma unroll
            for (int j = 0; j < 8; ++j) {
                acc0 = fmaf(ww[j], (float)vv[j][0], acc0);
                acc1 = fmaf(ww[j], (float)vv[j][1], acc1);
            }
        }
        for (; i + 2 <= cnt; i += 2) {
            int s0 = __shfl(es, i, 64);     float w0 = __shfl(ew, i, 64);
            int s1 = __shfl(es, i + 1, 64); float w1 = __shfl(ew, i + 1, 64);
            half2v v0 = *(const half2v*)(hlin + (size_t)s0 * COLS + c0);
            half2v v1 = *(const half2v*)(hlin + (size_t)s1 * COLS + c0);
            acc0 = fmaf(w0, (float)v0[0], acc0); acc1 = fmaf(w0, (float)v0[1], acc1);
            acc0 = fmaf(w1, (float)v1[0], acc0); acc1 = fmaf(w1, (float)v1[1], acc1);
        }
        if (i < cnt) {
            int s = __shfl(es, i, 64); float w = __shfl(ew, i, 64);
            half2v v = *(const half2v*)(hlin + (size_t)s * COLS + c0);
            acc0 = fmaf(w, (float)v[0], acc0); acc1 = fmaf(w, (float)v[1], acc1);
        }
    }
    float h0 = fmaxf(acc0 + bias[c0], 0.0f);
    float h1 = fmaxf(acc1 + bias[c0 + 1], 0.0f);
    #pragma unroll
    for (int c = 0; c < 9; ++c) {
        float p = h0 * Ws[c][c0] + h1 * Ws[c][c0 + 1];
        #pragma unroll
        for (int m = 1; m < 64; m <<= 1) p += __shfl_xor(p, m, 64);
        if (lane == 0) out[(size_t)node * 9 + c] = p + bs[c];
    }
}

// ---------------- launch ----------------

extern "C" void kernel_launch(void* const* d_in, const int* in_sizes, int n_in,
                              void* d_out, int out_size, void* d_ws, size_t ws_size,
                              hipStream_t stream) {
    const float* x  = (const float*)d_in[0];
    const int*   ei = (const int*)d_in[1];
    const float* W1 = (const float*)d_in[2];
    const float* b1 = (const float*)d_in[3];
    const float* W2 = (const float*)d_in[4];
    const float* b2 = (const float*)d_in[5];
    const float* W3 = (const float*)d_in[6];
    const float* b3 = (const float*)d_in[7];
    const float* We = (const float*)d_in[8];
    const float* be = (const float*)d_in[9];
    const float* Wh = (const float*)d_in[10];
    const float* bh = (const float*)d_in[11];
    const float* Wg = (const float*)d_in[12];
    const float* bg = (const float*)d_in[13];
    float* out = (float*)d_out;

    const int* src = ei;
    const int* dst = ei + N_EDGES;

    char* ws = (char*)d_ws;
    size_t off = 0;
    auto alloc = [&](size_t bytes) {
        void* p = ws + off;
        off = (off + bytes + 255) & ~(size_t)255;
        return p;
    };
    int*   deg       = (int*)alloc(N_NODES * 4);
    float* dinv      = (float*)alloc(N_NODES * 4);
    int*   row_start = (int*)alloc((N_NODES + 1) * 4);
    int*   cursor    = (int*)alloc(N_NODES * 4);
    int*   csr_src   = (int*)alloc(N_EDGES * 4);
    float* csr_w     = (float*)alloc(N_EDGES * 4);
    unsigned short* Xh = (unsigned short*)alloc((size_t)MP * 512 * 2);  // reused as H_hi [MP][256]
    unsigned short* Xl = (unsigned short*)alloc((size_t)MP * 512 * 2);  // reused as H_lo
    f16* Cbuf = (f16*)alloc((size_t)MP * 256 * 2);                      // fp16 GEMM out (gather table)
    unsigned short* W1h = (unsigned short*)alloc(512 * 256 * 2);
    unsigned short* W1l = (unsigned short*)alloc(512 * 256 * 2);
    unsigned short* W2h = (unsigned short*)alloc(256 * 256 * 2);
    unsigned short* W2l = (unsigned short*)alloc(256 * 256 * 2);
    unsigned short* W3h = (unsigned short*)alloc(256 * 128 * 2);
    unsigned short* W3l = (unsigned short*)alloc(256 * 128 * 2);

    unsigned short* Hh = Xh;   // x no longer needed once gemm1 is done
    unsigned short* Hl = Xl;

    hipMemsetAsync(deg, 0, N_NODES * 4, stream);
    hipMemsetAsync(cursor, 0, N_NODES * 4, stream);

    hist_kernel<<<(N_EDGES + 255) / 256, 256, 0, stream>>>(dst, deg, N_EDGES);
    dinv_kernel<<<(N_NODES + 255) / 256, 256, 0, stream>>>(deg, dinv, N_NODES);
    scan_kernel<<<1, 1024, 0, stream>>>(deg, row_start, N_NODES);
    scatter_kernel<<<(N_EDGES + 255) / 256, 256, 0, stream>>>(src, dst, dinv, row_start, cursor,
                                                              csr_src, csr_w, N_EDGES);

    wsplit_kernel<<<(512 * 256 + 255) / 256, 256, 0, stream>>>(W1, W1h, W1l, 512, 256);
    wsplit_kernel<<<(256 * 256 + 255) / 256, 256, 0, stream>>>(W2, W2h, W2l, 256, 256);
    wsplit_kernel<<<(256 * 128 + 255) / 256, 256, 0, stream>>>(W3, W3h, W3l, 256, 128);
    xsplit_kernel<<<(N_NODES * 512 / 4 + 255) / 256, 256, 0, stream>>>(x, Xh, Xl, N_NODES * 512 / 4);

    dim3 blk(256);
    // layer 1
    gemm_mfma<<<dim3(2, MP / 128), blk, 0, stream>>>(Xh, Xl, W1h, W1l, Cbuf, N_NODES, 256, 512);
    aggregate4_kernel<<<(N_NODES + 3) / 4, blk, 0, stream>>>(
        Cbuf, row_start, csr_src, csr_w, dinv, b1, Hh, Hl, N_NODES);
    // layer 2
    gemm_mfma<<<dim3(2, MP / 128), blk, 0, stream>>>(Hh, Hl, W2h, W2l, Cbuf, N_NODES, 256, 256);
    aggregate4_kernel<<<(N_NODES + 3) / 4, blk, 0, stream>>>(
        Cbuf, row_start, csr_src, csr_w, dinv, b2, Hh, Hl, N_NODES);
    // layer 3 (N=128) + fused heads
    gemm_mfma<<<dim3(1, MP / 128), blk, 0, stream>>>(Hh, Hl, W3h, W3l, Cbuf, N_NODES, 128, 256);
    agg_head_kernel<<<(N_NODES + 3) / 4, blk, 0, stream>>>(
        Cbuf, row_start, csr_src, csr_w, dinv, b3, We, be, Wh, bh, Wg, bg, out, N_NODES);
}

// Round 11
// 576.549 us; speedup vs baseline: 1.6654x; 1.0718x over previous
//
#include <hip/hip_runtime.h>

#define N_NODES 50000
#define N_EDGES 800000
#define MP 50048   // padded rows = 391 * 128

typedef __attribute__((ext_vector_type(8))) short bf16x8;
typedef __attribute__((ext_vector_type(4))) float f32x4;
typedef _Float16 f16;
typedef __attribute__((ext_vector_type(4))) _Float16 half4;
typedef __attribute__((ext_vector_type(2))) _Float16 half2v;

__device__ __forceinline__ unsigned short f2bf(float f) {
    unsigned u = __float_as_uint(f);
    u += 0x7fffu + ((u >> 16) & 1u);
    return (unsigned short)(u >> 16);
}
__device__ __forceinline__ float bf2f(unsigned short h) {
    return __uint_as_float(((unsigned)h) << 16);
}

// ---------------- CSR build ----------------

__global__ void hist_kernel(const int* __restrict__ dst, int* __restrict__ deg, int e) {
    int i = blockIdx.x * blockDim.x + threadIdx.x;
    if (i < e) atomicAdd(&deg[dst[i]], 1);
}

__global__ void dinv_kernel(const int* __restrict__ deg, float* __restrict__ dinv, int n) {
    int i = blockIdx.x * blockDim.x + threadIdx.x;
    if (i < n) dinv[i] = rsqrtf((float)deg[i] + 1.0f);
}

__global__ __launch_bounds__(1024) void scan_kernel(const int* __restrict__ counts,
                                                    int* __restrict__ row_start, int n) {
    __shared__ int wsum[16];
    __shared__ int carry_s;
    int tid = threadIdx.x, wid = tid >> 6, lane = tid & 63;
    if (tid == 0) carry_s = 0;
    __syncthreads();
    for (int base = 0; base < n; base += 1024) {
        int i = base + tid;
        int v = (i < n) ? counts[i] : 0;
        int s = v;
        #pragma unroll
        for (int off = 1; off < 64; off <<= 1) {
            int t = __shfl_up(s, off, 64);
            if (lane >= off) s += t;
        }
        if (lane == 63) wsum[wid] = s;
        __syncthreads();
        if (wid == 0) {
            int ws = (lane < 16) ? wsum[lane] : 0;
            #pragma unroll
            for (int off = 1; off < 16; off <<= 1) {
                int t = __shfl_up(ws, off, 64);
                if (lane >= off) ws += t;
            }
            if (lane < 16) wsum[lane] = ws;
        }
        __syncthreads();
        int carry = carry_s;
        if (i < n) row_start[i] = carry + ((wid == 0) ? 0 : wsum[wid - 1]) + s - v;
        int total = wsum[15];
        __syncthreads();
        if (tid == 0) carry_s = carry + total;
        __syncthreads();
    }
    if (tid == 0) row_start[n] = carry_s;
}

// csr_sw[i] = (src, bits(w)) — int2 so edge metadata scalar-loads as one dwordx2
__global__ void scatter_kernel(const int* __restrict__ src, const int* __restrict__ dst,
                               const float* __restrict__ dinv,
                               const int* __restrict__ row_start, int* __restrict__ cursor,
                               int2* __restrict__ csr_sw, int e) {
    int i = blockIdx.x * blockDim.x + threadIdx.x;
    if (i < e) {
        int d = dst[i], s = src[i];
        int p = atomicAdd(&cursor[d], 1);
        int idx = row_start[d] + p;
        csr_sw[idx] = make_int2(s, __float_as_int(dinv[s] * dinv[d]));
    }
}

// ---------------- fused: zero deg/cursor + all 3 weight transposes/splits ----------------
// grid = (131072 + 65536 + 32768) / 256 = 896 blocks exactly.

__global__ void wsplit3_kernel(const float* __restrict__ W1, unsigned short* __restrict__ W1h,
                               unsigned short* __restrict__ W1l,
                               const float* __restrict__ W2, unsigned short* __restrict__ W2h,
                               unsigned short* __restrict__ W2l,
                               const float* __restrict__ W3, unsigned short* __restrict__ W3h,
                               unsigned short* __restrict__ W3l,
                               int* __restrict__ deg, int* __restrict__ cursor) {
    int gi = blockIdx.x * blockDim.x + threadIdx.x;
    if (gi < N_NODES) { deg[gi] = 0; cursor[gi] = 0; }
    const float* W; unsigned short *Wh_, *Wl_; int K, N, i = gi;
    if (i < 131072)      { W = W1; Wh_ = W1h; Wl_ = W1l; K = 512; N = 256; }
    else if (i < 196608) { i -= 131072; W = W2; Wh_ = W2h; Wl_ = W2l; K = 256; N = 256; }
    else                 { i -= 196608; W = W3; Wh_ = W3h; Wl_ = W3l; K = 256; N = 128; }
    int k = i / N, n = i - k * N;
    float v = W[i];
    unsigned short h = f2bf(v);
    unsigned short l = f2bf(v - bf2f(h));
    Wh_[(size_t)n * K + k] = h;
    Wl_[(size_t)n * K + k] = l;
}

// ---------------- x -> bf16 hi/lo split ----------------

__global__ void xsplit_kernel(const float* __restrict__ x, unsigned short* __restrict__ Xh,
                              unsigned short* __restrict__ Xl, int total4) {
    int i = blockIdx.x * blockDim.x + threadIdx.x;
    if (i >= total4) return;
    float4 v = ((const float4*)x)[i];
    ushort4 h, l;
    h.x = f2bf(v.x); l.x = f2bf(v.x - bf2f(h.x));
    h.y = f2bf(v.y); l.y = f2bf(v.y - bf2f(h.y));
    h.z = f2bf(v.z); l.z = f2bf(v.z - bf2f(h.z));
    h.w = f2bf(v.w); l.w = f2bf(v.w - bf2f(h.w));
    ((ushort4*)Xh)[i] = h;
    ((ushort4*)Xl)[i] = l;
}

// ---------------- bf16x3 MFMA GEMM: C[M][N] = (Ah+Al)[M][K] @ (Bh+Bl)^T[N][K], fp16 out ----------------

__global__ __launch_bounds__(256) void gemm_mfma(
    const unsigned short* __restrict__ Ah, const unsigned short* __restrict__ Al,
    const unsigned short* __restrict__ Bh, const unsigned short* __restrict__ Bl,
    f16* __restrict__ C, int M, int N, int K) {
    __shared__ __align__(16) char smem[32768];
    const int tid = threadIdx.x;
    const int wid = tid >> 6, lane = tid & 63;
    const int wr = wid >> 1, wc = wid & 1;
    const int rl = lane & 15, kg = lane >> 4;
    const int bn = blockIdx.x * 128;
    const int bm = blockIdx.y * 128;
    const size_t K2 = (size_t)K * 2;   // row bytes

    const int c0 = tid, r0 = c0 >> 2, g10 = c0 & 3;
    const int c1 = tid + 256, r1 = c1 >> 2, g11 = c1 & 3;
    const int g0 = (g10 - (r0 >> 1)) & 3;
    const int g1 = (g11 - (r1 >> 1)) & 3;

    const char* pAh0 = (const char*)Ah + (size_t)(bm + r0) * K2 + g0 * 16;
    const char* pAh1 = (const char*)Ah + (size_t)(bm + r1) * K2 + g1 * 16;
    const char* pAl0 = (const char*)Al + (size_t)(bm + r0) * K2 + g0 * 16;
    const char* pAl1 = (const char*)Al + (size_t)(bm + r1) * K2 + g1 * 16;
    const char* pBh0 = (const char*)Bh + (size_t)(bn + r0) * K2 + g0 * 16;
    const char* pBh1 = (const char*)Bh + (size_t)(bn + r1) * K2 + g1 * 16;
    const char* pBl0 = (const char*)Bl + (size_t)(bn + r0) * K2 + g0 * 16;
    const char* pBl1 = (const char*)Bl + (size_t)(bn + r1) * K2 + g1 * 16;

    const int lds_t0 = wid * 1024;
    const int lds_t1 = 4096 + wid * 1024;

    const int gp = (kg + (rl >> 1)) & 3;
    int offA[4], offB[4];
    #pragma unroll
    for (int m = 0; m < 4; ++m) offA[m] = (wr * 64 + m * 16 + rl) * 64 + gp * 16;
    #pragma unroll
    for (int n = 0; n < 4; ++n) offB[n] = (wc * 64 + n * 16 + rl) * 64 + gp * 16;

    f32x4 acc[4][4];
    #pragma unroll
    for (int m = 0; m < 4; ++m)
        #pragma unroll
        for (int n = 0; n < 4; ++n) acc[m][n] = (f32x4){0.f, 0.f, 0.f, 0.f};

#define GLOAD(g, loff)                                                                   \
    __builtin_amdgcn_global_load_lds((const __attribute__((address_space(1))) void*)(g), \
                                     (__attribute__((address_space(3))) void*)(smem + (loff)), \
                                     16, 0, 0)

    const int nk = K >> 5;
    for (int it = 0; it < nk; ++it) {
        const size_t kb = (size_t)it * 64;
        if (it) __syncthreads();
        GLOAD(pAh0 + kb, 0     + lds_t0);  GLOAD(pAh1 + kb, 0     + lds_t1);
        GLOAD(pAl0 + kb, 8192  + lds_t0);  GLOAD(pAl1 + kb, 8192  + lds_t1);
        GLOAD(pBh0 + kb, 16384 + lds_t0);  GLOAD(pBh1 + kb, 16384 + lds_t1);
        GLOAD(pBl0 + kb, 24576 + lds_t0);  GLOAD(pBl1 + kb, 24576 + lds_t1);
        __syncthreads();

        bf16x8 fah[4], fal[4], fbh[4], fbl[4];
        #pragma unroll
        for (int m = 0; m < 4; ++m) {
            fah[m] = *(const bf16x8*)(smem + offA[m]);
            fal[m] = *(const bf16x8*)(smem + 8192 + offA[m]);
        }
        #pragma unroll
        for (int n = 0; n < 4; ++n) {
            fbh[n] = *(const bf16x8*)(smem + 16384 + offB[n]);
            fbl[n] = *(const bf16x8*)(smem + 24576 + offB[n]);
        }
        #pragma unroll
        for (int m = 0; m < 4; ++m)
            #pragma unroll
            for (int n = 0; n < 4; ++n) {
                acc[m][n] = __builtin_amdgcn_mfma_f32_16x16x32_bf16(fah[m], fbh[n], acc[m][n], 0, 0, 0);
                acc[m][n] = __builtin_amdgcn_mfma_f32_16x16x32_bf16(fah[m], fbl[n], acc[m][n], 0, 0, 0);
                acc[m][n] = __builtin_amdgcn_mfma_f32_16x16x32_bf16(fal[m], fbh[n], acc[m][n], 0, 0, 0);
            }
    }
#undef GLOAD

    // C/D layout: col = lane&15, row = (lane>>4)*4 + reg  [m89-verified]
    #pragma unroll
    for (int m = 0; m < 4; ++m) {
        const int rbase = bm + wr * 64 + m * 16 + kg * 4;
        #pragma unroll
        for (int n = 0; n < 4; ++n) {
            const int col = bn + wc * 64 + n * 16 + rl;
            f32x4 v = acc[m][n];
            #pragma unroll
            for (int j = 0; j < 4; ++j) {
                int row = rbase + j;
                if (row < M) C[(size_t)row * N + col] = (f16)v[j];
            }
        }
    }
}

// ---------------- aggregation (256 cols): bf16 hi/lo out = relu(A_hat @ hlin + bias) ----------------
// one wave per node. Edge metadata is wave-uniform -> readfirstlane + scalar loads
// (s_load of int2); vector pipe issues ONLY the 16-deep independent fp16 row gathers.

__global__ __launch_bounds__(256) void aggregate4_kernel(
    const f16* __restrict__ hlin, const int* __restrict__ row_start,
    const int2* __restrict__ csr_sw,
    const float* __restrict__ dinv, const float* __restrict__ bias,
    unsigned short* __restrict__ oh, unsigned short* __restrict__ ol, int n) {
    constexpr int COLS = 256;
    int node = blockIdx.x * 4 + (threadIdx.x >> 6);
    int lane = threadIdx.x & 63;
    if (node >= n) return;
    int c0 = lane * 4;

    float acc[4];
    float dn = dinv[node];
    float ns = dn * dn;
    {
        half4 v = *(const half4*)(hlin + (size_t)node * COLS + c0);
        #pragma unroll
        for (int k = 0; k < 4; ++k) acc[k] = (float)v[k] * ns;
    }
    int beg = __builtin_amdgcn_readfirstlane(row_start[node]);
    int end = __builtin_amdgcn_readfirstlane(row_start[node + 1]);

    int j = beg;
    for (; j + 16 <= end; j += 16) {
        int2 e[16]; half4 vv[16];
        #pragma unroll
        for (int t = 0; t < 16; ++t) e[t] = csr_sw[j + t];
        #pragma unroll
        for (int t = 0; t < 16; ++t)
            vv[t] = *(const half4*)(hlin + (size_t)e[t].x * COLS + c0);
        #pragma unroll
        for (int t = 0; t < 16; ++t) {
            float w = __int_as_float(e[t].y);
            #pragma unroll
            for (int k = 0; k < 4; ++k) acc[k] = fmaf(w, (float)vv[t][k], acc[k]);
        }
    }
    for (; j + 4 <= end; j += 4) {
        int2 e[4]; half4 vv[4];
        #pragma unroll
        for (int t = 0; t < 4; ++t) e[t] = csr_sw[j + t];
        #pragma unroll
        for (int t = 0; t < 4; ++t)
            vv[t] = *(const half4*)(hlin + (size_t)e[t].x * COLS + c0);
        #pragma unroll
        for (int t = 0; t < 4; ++t) {
            float w = __int_as_float(e[t].y);
            #pragma unroll
            for (int k = 0; k < 4; ++k) acc[k] = fmaf(w, (float)vv[t][k], acc[k]);
        }
    }
    for (; j < end; ++j) {
        int2 e = csr_sw[j];
        half4 v = *(const half4*)(hlin + (size_t)e.x * COLS + c0);
        float w = __int_as_float(e.y);
        #pragma unroll
        for (int k = 0; k < 4; ++k) acc[k] = fmaf(w, (float)v[k], acc[k]);
    }
    unsigned short hv[4], lv[4];
    #pragma unroll
    for (int v = 0; v < 4; ++v) {
        float val = fmaxf(acc[v] + bias[c0 + v], 0.0f);
        hv[v] = f2bf(val);
        lv[v] = f2bf(val - bf2f(hv[v]));
    }
    *(ushort4*)(oh + (size_t)node * COLS + c0) = make_ushort4(hv[0], hv[1], hv[2], hv[3]);
    *(ushort4*)(ol + (size_t)node * COLS + c0) = make_ushort4(lv[0], lv[1], lv[2], lv[3]);
}

// ---------------- fused layer-3 aggregation (128 cols) + 3-head output ----------------
// No LDS at all: each lane keeps its 18 head-weight values in registers (eliminates the
// stride-2 LDS bank conflicts, 900K/dispatch). Scalar edge metadata; reduction loops
// swapped so the 9 shfl_xor trees run with 9-way ILP (chain depth 6, not 54).

__global__ __launch_bounds__(256) void agg_head_kernel(
    const f16* __restrict__ hlin, const int* __restrict__ row_start,
    const int2* __restrict__ csr_sw,
    const float* __restrict__ dinv, const float* __restrict__ bias,
    const float* __restrict__ We, const float* __restrict__ be,
    const float* __restrict__ Wh, const float* __restrict__ bh,
    const float* __restrict__ Wg, const float* __restrict__ bg,
    float* __restrict__ out, int n) {
    constexpr int COLS = 128;
    int node = blockIdx.x * 4 + (threadIdx.x >> 6);
    int lane = threadIdx.x & 63;
    if (node >= n) return;
    int c0 = lane * 2;

    // per-lane head weights for rows c0, c0+1 (We|Wh|Wg are [128][3] row-major)
    float w0r[9], w1r[9];
    #pragma unroll
    for (int c = 0; c < 3; ++c) {
        w0r[c]     = We[c0 * 3 + c];       w1r[c]     = We[(c0 + 1) * 3 + c];
        w0r[c + 3] = Wh[c0 * 3 + c];       w1r[c + 3] = Wh[(c0 + 1) * 3 + c];
        w0r[c + 6] = Wg[c0 * 3 + c];       w1r[c + 6] = Wg[(c0 + 1) * 3 + c];
    }

    float acc0, acc1;
    float dn = dinv[node];
    float ns = dn * dn;
    {
        half2v v = *(const half2v*)(hlin + (size_t)node * COLS + c0);
        acc0 = (float)v[0] * ns; acc1 = (float)v[1] * ns;
    }
    int beg = __builtin_amdgcn_readfirstlane(row_start[node]);
    int end = __builtin_amdgcn_readfirstlane(row_start[node + 1]);

    int j = beg;
    for (; j + 16 <= end; j += 16) {
        int2 e[16]; half2v vv[16];
        #pragma unroll
        for (int t = 0; t < 16; ++t) e[t] = csr_sw[j + t];
        #pragma unroll
        for (int t = 0; t < 16; ++t)
            vv[t] = *(const half2v*)(hlin + (size_t)e[t].x * COLS + c0);
        #pragma unroll
        for (int t = 0; t < 16; ++t) {
            float w = __int_as_float(e[t].y);
            acc0 = fmaf(w, (float)vv[t][0], acc0);
            acc1 = fmaf(w, (float)vv[t][1], acc1);
        }
    }
    for (; j + 4 <= end; j += 4) {
        int2 e[4]; half2v vv[4];
        #pragma unroll
        for (int t = 0; t < 4; ++t) e[t] = csr_sw[j + t];
        #pragma unroll
        for (int t = 0; t < 4; ++t)
            vv[t] = *(const half2v*)(hlin + (size_t)e[t].x * COLS + c0);
        #pragma unroll
        for (int t = 0; t < 4; ++t) {
            float w = __int_as_float(e[t].y);
            acc0 = fmaf(w, (float)vv[t][0], acc0);
            acc1 = fmaf(w, (float)vv[t][1], acc1);
        }
    }
    for (; j < end; ++j) {
        int2 e = csr_sw[j];
        half2v v = *(const half2v*)(hlin + (size_t)e.x * COLS + c0);
        float w = __int_as_float(e.y);
        acc0 = fmaf(w, (float)v[0], acc0);
        acc1 = fmaf(w, (float)v[1], acc1);
    }
    float h0 = fmaxf(acc0 + bias[c0], 0.0f);
    float h1 = fmaxf(acc1 + bias[c0 + 1], 0.0f);

    float p[9];
    #pragma unroll
    for (int c = 0; c < 9; ++c) p[c] = h0 * w0r[c] + h1 * w1r[c];
    #pragma unroll
    for (int m = 1; m < 64; m <<= 1)
        #pragma unroll
        for (int c = 0; c < 9; ++c) p[c] += __shfl_xor(p[c], m, 64);
    if (lane == 0) {
        #pragma unroll
        for (int c = 0; c < 9; ++c) {
            float b = (c < 3) ? be[c] : (c < 6) ? bh[c - 3] : bg[c - 6];
            out[(size_t)node * 9 + c] = p[c] + b;
        }
    }
}

// ---------------- launch ----------------

extern "C" void kernel_launch(void* const* d_in, const int* in_sizes, int n_in,
                              void* d_out, int out_size, void* d_ws, size_t ws_size,
                              hipStream_t stream) {
    const float* x  = (const float*)d_in[0];
    const int*   ei = (const int*)d_in[1];
    const float* W1 = (const float*)d_in[2];
    const float* b1 = (const float*)d_in[3];
    const float* W2 = (const float*)d_in[4];
    const float* b2 = (const float*)d_in[5];
    const float* W3 = (const float*)d_in[6];
    const float* b3 = (const float*)d_in[7];
    const float* We = (const float*)d_in[8];
    const float* be = (const float*)d_in[9];
    const float* Wh = (const float*)d_in[10];
    const float* bh = (const float*)d_in[11];
    const float* Wg = (const float*)d_in[12];
    const float* bg = (const float*)d_in[13];
    float* out = (float*)d_out;

    const int* src = ei;
    const int* dst = ei + N_EDGES;

    char* ws = (char*)d_ws;
    size_t off = 0;
    auto alloc = [&](size_t bytes) {
        void* p = ws + off;
        off = (off + bytes + 255) & ~(size_t)255;
        return p;
    };
    int*   deg       = (int*)alloc(N_NODES * 4);
    float* dinv      = (float*)alloc(N_NODES * 4);
    int*   row_start = (int*)alloc((N_NODES + 1) * 4);
    int*   cursor    = (int*)alloc(N_NODES * 4);
    int2*  csr_sw    = (int2*)alloc((size_t)N_EDGES * 8);
    unsigned short* Xh = (unsigned short*)alloc((size_t)MP * 512 * 2);  // reused as H_hi [MP][256]
    unsigned short* Xl = (unsigned short*)alloc((size_t)MP * 512 * 2);  // reused as H_lo
    f16* Cbuf = (f16*)alloc((size_t)MP * 256 * 2);                      // fp16 GEMM out (gather table)
    unsigned short* W1h = (unsigned short*)alloc(512 * 256 * 2);
    unsigned short* W1l = (unsigned short*)alloc(512 * 256 * 2);
    unsigned short* W2h = (unsigned short*)alloc(256 * 256 * 2);
    unsigned short* W2l = (unsigned short*)alloc(256 * 256 * 2);
    unsigned short* W3h = (unsigned short*)alloc(256 * 128 * 2);
    unsigned short* W3l = (unsigned short*)alloc(256 * 128 * 2);

    unsigned short* Hh = Xh;   // x no longer needed once gemm1 is done
    unsigned short* Hl = Xl;

    // wsplit3 also zeroes deg/cursor (stream-ordered before hist/scatter)
    wsplit3_kernel<<<896, 256, 0, stream>>>(W1, W1h, W1l, W2, W2h, W2l, W3, W3h, W3l,
                                            deg, cursor);
    xsplit_kernel<<<(N_NODES * 512 / 4 + 255) / 256, 256, 0, stream>>>(x, Xh, Xl, N_NODES * 512 / 4);

    hist_kernel<<<(N_EDGES + 255) / 256, 256, 0, stream>>>(dst, deg, N_EDGES);
    dinv_kernel<<<(N_NODES + 255) / 256, 256, 0, stream>>>(deg, dinv, N_NODES);
    scan_kernel<<<1, 1024, 0, stream>>>(deg, row_start, N_NODES);
    scatter_kernel<<<(N_EDGES + 255) / 256, 256, 0, stream>>>(src, dst, dinv, row_start, cursor,
                                                              csr_sw, N_EDGES);

    dim3 blk(256);
    // layer 1
    gemm_mfma<<<dim3(2, MP / 128), blk, 0, stream>>>(Xh, Xl, W1h, W1l, Cbuf, N_NODES, 256, 512);
    aggregate4_kernel<<<(N_NODES + 3) / 4, blk, 0, stream>>>(
        Cbuf, row_start, csr_sw, dinv, b1, Hh, Hl, N_NODES);
    // layer 2
    gemm_mfma<<<dim3(2, MP / 128), blk, 0, stream>>>(Hh, Hl, W2h, W2l, Cbuf, N_NODES, 256, 256);
    aggregate4_kernel<<<(N_NODES + 3) / 4, blk, 0, stream>>>(
        Cbuf, row_start, csr_sw, dinv, b2, Hh, Hl, N_NODES);
    // layer 3 (N=128) + fused heads
    gemm_mfma<<<dim3(1, MP / 128), blk, 0, stream>>>(Hh, Hl, W3h, W3l, Cbuf, N_NODES, 128, 256);
    agg_head_kernel<<<(N_NODES + 3) / 4, blk, 0, stream>>>(
        Cbuf, row_start, csr_sw, dinv, b3, We, be, Wh, bh, Wg, bg, out, N_NODES);
}